// Round 3
// baseline (2176.238 us; speedup 1.0000x reference)
//
#include <hip/hip_runtime.h>
#include <hip/hip_bf16.h>
#include <math.h>

#define NNODES 50000
#define NEDGES 800000
#define SDIM   128
#define HDIM   256
#define NROWS  9
#define TOTROWS (NNODES * NROWS)   // 450000

typedef _Float16 f16;
typedef _Float16 f16x8 __attribute__((ext_vector_type(8)));
typedef _Float16 f16x4 __attribute__((ext_vector_type(4)));
typedef float    f32x4 __attribute__((ext_vector_type(4)));

__device__ __forceinline__ float silu(float x) { return x / (1.0f + __expf(-x)); }

__device__ __forceinline__ f16x8 zero8() {
    f16x8 v;
    #pragma unroll
    for (int i = 0; i < 8; ++i) v[i] = (f16)0.0f;
    return v;
}

// ---------------------------------------------------------------------------
// Weight transpose + f16 convert. Dest layouts: [out_col][k] (K-contiguous).
// ---------------------------------------------------------------------------
__global__ __launch_bounds__(256) void wprep_k(
    const float* __restrict__ W1, const float* __restrict__ W2,
    const float* __restrict__ Wg1, const float* __restrict__ Wg2,
    f16* __restrict__ W1T, f16* __restrict__ W2T,
    f16* __restrict__ Wg1T, f16* __restrict__ Wg2T)
{
    int i = blockIdx.x * 256 + threadIdx.x;
    if (i < 32768) {  // W1T[n=256][k=128]
        int n = i >> 7, k = i & 127;
        W1T[i] = (f16)W1[k * 256 + n];
    }
    if (i < 32768) {  // W2T[s=128][k=256]
        int s = i >> 8, k = i & 255;
        W2T[i] = (f16)W2[k * 128 + s];
    }
    if (i < 393216) { // Wg1T[l][h=256][k=512]
        int l = i >> 17, r = i & 131071;
        int h = r >> 9, k = r & 511;
        Wg1T[i] = (f16)Wg1[l * 131072 + k * 256 + h];
    }
    if (i < 196608) { // Wg2T[l][h=256][k=256]
        int l = i >> 16, r = i & 65535;
        int h = r >> 8, k = r & 255;
        Wg2T[i] = (f16)Wg2[l * 65536 + k * 256 + h];
    }
}

// ---------------------------------------------------------------------------
// Per-node prep: x0 slot of gate base + norms (f16).
// base per node: [c_i(128) | c_ang(128) | x0(128)]
// ---------------------------------------------------------------------------
__global__ __launch_bounds__(256) void prep_k(
    const float* __restrict__ x, f16* __restrict__ base, f16* __restrict__ norms)
{
    int t = threadIdx.x;
    int node = blockIdx.x * 2 + (t >> 7);
    int c = t & 127;
    const float* xr = x + (size_t)node * (NROWS * SDIM) + c;
    float v0 = xr[0];
    float s1 = 0.0f, s2 = 0.0f;
    #pragma unroll
    for (int r = 1; r < 4; ++r) { float v = xr[r * 128]; s1 += v * v; }
    #pragma unroll
    for (int r = 4; r < 9; ++r) { float v = xr[r * 128]; s2 += v * v; }
    base[(size_t)node * 384 + 256 + c] = (f16)v0;
    norms[(size_t)node * 128 + c]                = (f16)fabsf(v0);
    norms[((size_t)NNODES + node) * 128 + c]     = (f16)sqrtf(s1);
    norms[((size_t)2 * NNODES + node) * 128 + c] = (f16)sqrtf(s2);
}

// ---------------------------------------------------------------------------
// CSR build
// ---------------------------------------------------------------------------
__global__ __launch_bounds__(256) void hist_k(const int* __restrict__ dst, int* __restrict__ cnt)
{
    int e = blockIdx.x * 256 + threadIdx.x;
    if (e < NEDGES) atomicAdd(&cnt[dst[e]], 1);
}

__global__ __launch_bounds__(1024) void scan_k(const int* __restrict__ cnt, int* __restrict__ row_start)
{
    __shared__ int part[1024];
    int t = threadIdx.x;
    int lo = t * 49, hi = min(lo + 49, NNODES);
    int s = 0;
    for (int i = lo; i < hi; ++i) s += cnt[i];
    part[t] = s;
    __syncthreads();
    for (int off = 1; off < 1024; off <<= 1) {
        int v = (t >= off) ? part[t - off] : 0;
        __syncthreads();
        part[t] += v;
        __syncthreads();
    }
    int run = part[t] - s;
    for (int i = lo; i < hi; ++i) { row_start[i] = run; run += cnt[i]; }
}

__global__ __launch_bounds__(256) void fill_k(
    const int* __restrict__ dst, const int* __restrict__ row_start,
    int* __restrict__ cur, int* __restrict__ eids)
{
    int e = blockIdx.x * 256 + threadIdx.x;
    if (e >= NEDGES) return;
    int d = dst[e];
    int p = atomicAdd(&cur[d], 1);
    eids[row_start[d] + p] = e;
}

// ---------------------------------------------------------------------------
// Gather means: wave per node, 2 edges in flight (32 lanes x float4 each).
// ---------------------------------------------------------------------------
__global__ __launch_bounds__(256) void gather_k(
    const float* __restrict__ t_ij, const float* __restrict__ a_ij,
    const int* __restrict__ row_start, const int* __restrict__ cnt,
    const int* __restrict__ eids, f16* __restrict__ base)
{
    int wv = threadIdx.x >> 6, ln = threadIdx.x & 63;
    int node = blockIdx.x * 4 + wv;
    int rs = row_start[node];
    int n  = cnt[node];
    int half = ln >> 5, q = ln & 31;
    float4 tc = {0,0,0,0}, ac = {0,0,0,0};
    for (int i = half; i < n; i += 2) {
        int e = eids[rs + i];
        float4 tv = ((const float4*)t_ij)[(size_t)e * 32 + q];
        float4 av = ((const float4*)a_ij)[(size_t)e * 32 + q];
        tc.x += tv.x; tc.y += tv.y; tc.z += tv.z; tc.w += tv.w;
        ac.x += av.x; ac.y += av.y; ac.z += av.z; ac.w += av.w;
    }
    tc.x += __shfl_xor(tc.x, 32); tc.y += __shfl_xor(tc.y, 32);
    tc.z += __shfl_xor(tc.z, 32); tc.w += __shfl_xor(tc.w, 32);
    ac.x += __shfl_xor(ac.x, 32); ac.y += __shfl_xor(ac.y, 32);
    ac.z += __shfl_xor(ac.z, 32); ac.w += __shfl_xor(ac.w, 32);
    float inv = 1.0f / (float)(n > 0 ? n : 1);
    if (half == 0) {   // write c_i
        f16x4 v;
        v[0] = (f16)(tc.x * inv); v[1] = (f16)(tc.y * inv);
        v[2] = (f16)(tc.z * inv); v[3] = (f16)(tc.w * inv);
        *(f16x4*)(base + (size_t)node * 384 + q * 4) = v;
    } else {           // write c_ang
        f16x4 v;
        v[0] = (f16)(ac.x * inv); v[1] = (f16)(ac.y * inv);
        v[2] = (f16)(ac.z * inv); v[3] = (f16)(ac.w * inv);
        *(f16x4*)(base + (size_t)node * 384 + 128 + q * 4) = v;
    }
}

// ---------------------------------------------------------------------------
// Gate MLP for one l. 64 nodes/block, 4 waves x 16 nodes. A direct from
// global (no staging barriers); g1 wave-local in LDS; 1 barrier total.
// ---------------------------------------------------------------------------
__global__ __launch_bounds__(256, 3) void gate_k(
    const f16* __restrict__ base, const f16* __restrict__ norms,
    const f16* __restrict__ Wg1T, const f16* __restrict__ Wg2T,
    const float* __restrict__ bg1, const float* __restrict__ bg2,
    f16* __restrict__ g2out)
{
    const int l  = blockIdx.y;
    const int n0 = blockIdx.x * 64;
    const int t  = threadIdx.x;
    const int wv = t >> 6, ln = t & 63;
    const int col0 = ln & 15;
    const int kq   = ln >> 4;

    __shared__ f16 g1_lds[64][264];

    const int anode = n0 + wv * 16 + col0;   // A-fragment row (node)
    const bool av_ok = anode < NNODES;

    f32x4 acc[16];
    #pragma unroll
    for (int nt = 0; nt < 16; ++nt) {
        float b = bg1[l * 256 + nt * 16 + col0];
        f32x4 v = {b, b, b, b};
        acc[nt] = v;
    }

    const f16* wg1 = Wg1T + (size_t)l * 256 * 512;
    #pragma unroll
    for (int ks = 0; ks < 16; ++ks) {
        f16x8 a = zero8();
        if (av_ok) {
            const f16* src;
            if (ks < 8)       src = base  + (size_t)anode * 384 + ks * 32;
            else if (ks < 12) src = norms + ((size_t)l * NNODES + anode) * 128 + (ks - 8) * 32;
            else              src = base  + (size_t)anode * 384 + 256 + (ks - 12) * 32;
            a = *(const f16x8*)(src + kq * 8);
        }
        #pragma unroll
        for (int nt = 0; nt < 16; ++nt) {
            f16x8 b = *(const f16x8*)(wg1 + (size_t)(nt * 16 + col0) * 512 + ks * 32 + kq * 8);
            acc[nt] = __builtin_amdgcn_mfma_f32_16x16x32_f16(a, b, acc[nt], 0, 0, 0);
        }
    }

    // g1 = silu(acc) -> LDS (wave-local rows; same-wave ordering via lgkmcnt)
    #pragma unroll
    for (int nt = 0; nt < 16; ++nt)
        #pragma unroll
        for (int j = 0; j < 4; ++j)
            g1_lds[wv * 16 + kq * 4 + j][nt * 16 + col0] = (f16)silu(acc[nt][j]);

    f32x4 acc2[16];
    #pragma unroll
    for (int nt = 0; nt < 16; ++nt) {
        float b = bg2[l * 256 + nt * 16 + col0];
        f32x4 v = {b, b, b, b};
        acc2[nt] = v;
    }
    const f16* wg2 = Wg2T + (size_t)l * 256 * 256;
    #pragma unroll
    for (int ks = 0; ks < 8; ++ks) {
        f16x8 a = *(const f16x8*)&g1_lds[wv * 16 + col0][ks * 32 + kq * 8];
        #pragma unroll
        for (int nt = 0; nt < 16; ++nt) {
            f16x8 b = *(const f16x8*)(wg2 + (size_t)(nt * 16 + col0) * 256 + ks * 32 + kq * 8);
            acc2[nt] = __builtin_amdgcn_mfma_f32_16x16x32_f16(a, b, acc2[nt], 0, 0, 0);
        }
    }

    // g2 = silu(acc2) back into g1_lds (own rows), then coalesced copy out
    #pragma unroll
    for (int nt = 0; nt < 16; ++nt)
        #pragma unroll
        for (int j = 0; j < 4; ++j)
            g1_lds[wv * 16 + kq * 4 + j][nt * 16 + col0] = (f16)silu(acc2[nt][j]);
    __syncthreads();
    #pragma unroll
    for (int it = 0; it < 8; ++it) {
        int idx = t + 256 * it;          // 2048 chunks of 8 f16
        int row = idx >> 5, sg = idx & 31;
        int node = n0 + row;
        if (node < NNODES) {
            f16x8 v = *(const f16x8*)&g1_lds[row][sg * 8];
            *(f16x8*)(g2out + ((size_t)l * NNODES + node) * 256 + sg * 8) = v;
        }
    }
}

// ---------------------------------------------------------------------------
// Main fused: h = x@W1 ; gate; out = h@W2.  4 row-tiles of 64 per block,
// A direct from global, g prefetched to regs, 3 barriers/tile.
// ---------------------------------------------------------------------------
__global__ __launch_bounds__(256, 3) void main_k(
    const float* __restrict__ x, const f16* __restrict__ g2,
    const f16* __restrict__ W1T, const f16* __restrict__ W2T,
    float* __restrict__ out)
{
    const int t  = threadIdx.x;
    const int wv = t >> 6, ln = t & 63;
    const int col0 = ln & 15;
    const int kq   = ln >> 4;
    const int rowg = t >> 5;     // gate-pass base row (0..7)
    const int sg   = t & 31;     // gate-pass 16B column chunk

    __shared__ f16 hld[64][264];

    for (int tt = 0; tt < 4; ++tt) {
        const int r0 = blockIdx.x * 256 + tt * 64;

        // ---- prefetch gate rows into regs (row-major, coalesced) ----
        f16x8 gpre[8];
        #pragma unroll
        for (int u = 0; u < 8; ++u) {
            int gr = r0 + rowg + u * 8;
            gpre[u] = zero8();
            if (gr < TOTROWS) {
                int node = gr / 9, p = gr % 9;
                int l = (p > 0) + (p > 3);
                gpre[u] = *(const f16x8*)(g2 + ((size_t)l * NNODES + node) * 256 + sg * 8);
            }
        }

        // ---- GEMM1: A direct from x (f32->f16), B from W1T (L2) ----
        f32x4 acc[16];
        #pragma unroll
        for (int nt = 0; nt < 16; ++nt) { f32x4 z = {0,0,0,0}; acc[nt] = z; }
        const int arow = r0 + wv * 16 + col0;
        const bool a_ok = arow < TOTROWS;
        const float* asrc = x + (size_t)arow * 128 + kq * 8;
        #pragma unroll
        for (int ks = 0; ks < 4; ++ks) {
            f16x8 a = zero8();
            if (a_ok) {
                float4 f0 = *(const float4*)(asrc + ks * 32);
                float4 f1 = *(const float4*)(asrc + ks * 32 + 4);
                a[0] = (f16)f0.x; a[1] = (f16)f0.y; a[2] = (f16)f0.z; a[3] = (f16)f0.w;
                a[4] = (f16)f1.x; a[5] = (f16)f1.y; a[6] = (f16)f1.z; a[7] = (f16)f1.w;
            }
            #pragma unroll
            for (int nt = 0; nt < 16; ++nt) {
                f16x8 b = *(const f16x8*)(W1T + (size_t)(nt * 16 + col0) * 128 + ks * 32 + kq * 8);
                acc[nt] = __builtin_amdgcn_mfma_f32_16x16x32_f16(a, b, acc[nt], 0, 0, 0);
            }
        }
        // raw h -> LDS
        #pragma unroll
        for (int nt = 0; nt < 16; ++nt)
            #pragma unroll
            for (int j = 0; j < 4; ++j)
                hld[wv * 16 + kq * 4 + j][nt * 16 + col0] = (f16)acc[nt][j];
        __syncthreads();

        // ---- vectorized gating pass: h = (silu?) h * g ----
        #pragma unroll
        for (int u = 0; u < 8; ++u) {
            int row = rowg + u * 8;
            int gr  = r0 + row;
            int p   = gr % 9;
            f16x8 h = *(const f16x8*)&hld[row][sg * 8];
            f16x8 g = gpre[u];
            f16x8 r;
            if (p == 0) {
                #pragma unroll
                for (int i = 0; i < 8; ++i)
                    r[i] = (f16)(silu((float)h[i]) * (float)g[i]);
            } else {
                #pragma unroll
                for (int i = 0; i < 8; ++i)
                    r[i] = (f16)((float)h[i] * (float)g[i]);
            }
            *(f16x8*)&hld[row][sg * 8] = r;
        }
        __syncthreads();

        // ---- GEMM2: out = h @ W2 ----
        f32x4 acc2[8];
        #pragma unroll
        for (int nt = 0; nt < 8; ++nt) { f32x4 z = {0,0,0,0}; acc2[nt] = z; }
        #pragma unroll
        for (int ks = 0; ks < 8; ++ks) {
            f16x8 a = *(const f16x8*)&hld[wv * 16 + col0][ks * 32 + kq * 8];
            #pragma unroll
            for (int nt = 0; nt < 8; ++nt) {
                f16x8 b = *(const f16x8*)(W2T + (size_t)(nt * 16 + col0) * 256 + ks * 32 + kq * 8);
                acc2[nt] = __builtin_amdgcn_mfma_f32_16x16x32_f16(a, b, acc2[nt], 0, 0, 0);
            }
        }
        #pragma unroll
        for (int nt = 0; nt < 8; ++nt)
            #pragma unroll
            for (int j = 0; j < 4; ++j) {
                int gr = r0 + wv * 16 + kq * 4 + j;
                if (gr < TOTROWS) out[(size_t)gr * 128 + nt * 16 + col0] = acc2[nt][j];
            }
        __syncthreads();
    }
}

// ---------------------------------------------------------------------------
extern "C" void kernel_launch(void* const* d_in, const int* in_sizes, int n_in,
                              void* d_out, int out_size, void* d_ws, size_t ws_size,
                              hipStream_t stream) {
    const float* x_emb = (const float*)d_in[0];
    const float* t_ij  = (const float*)d_in[1];
    const float* a_ij  = (const float*)d_in[2];
    const int*   eidx  = (const int*)d_in[3];
    const float* W1  = (const float*)d_in[4];
    const float* W2  = (const float*)d_in[5];
    const float* Wg1 = (const float*)d_in[6];
    const float* bg1 = (const float*)d_in[7];
    const float* Wg2 = (const float*)d_in[8];
    const float* bg2 = (const float*)d_in[9];
    float* out = (float*)d_out;
    const int* dst = eidx + NEDGES;

    char* p = (char*)d_ws;
    int* cnt       = (int*)p;                 p += (size_t)NNODES * 4;
    int* cur       = (int*)p;                 p += (size_t)NNODES * 4;
    int* row_start = (int*)p;                 p += (size_t)(NNODES + 16) * 4;
    int* eids      = (int*)p;                 p += (size_t)NEDGES * 4;
    f16* base      = (f16*)p;                 p += (size_t)NNODES * 384 * 2;
    f16* norms     = (f16*)p;                 p += (size_t)3 * NNODES * 128 * 2;
    f16* g2b       = (f16*)p;                 p += (size_t)3 * NNODES * 256 * 2;
    f16* W1T       = (f16*)p;                 p += (size_t)32768 * 2;
    f16* W2T       = (f16*)p;                 p += (size_t)32768 * 2;
    f16* Wg1T      = (f16*)p;                 p += (size_t)393216 * 2;
    f16* Wg2T      = (f16*)p;                 p += (size_t)196608 * 2;

    hipMemsetAsync(cnt, 0, (size_t)2 * NNODES * 4, stream);  // cnt + cur

    wprep_k<<<1536, 256, 0, stream>>>(W1, W2, Wg1, Wg2, W1T, W2T, Wg1T, Wg2T);
    prep_k<<<NNODES / 2, 256, 0, stream>>>(x_emb, base, norms);
    hist_k<<<NEDGES / 256, 256, 0, stream>>>(dst, cnt);
    scan_k<<<1, 1024, 0, stream>>>(cnt, row_start);
    fill_k<<<NEDGES / 256, 256, 0, stream>>>(dst, row_start, cur, eids);
    gather_k<<<NNODES / 4, 256, 0, stream>>>(t_ij, a_ij, row_start, cnt, eids, base);
    dim3 gg((NNODES + 63) / 64, 3);
    gate_k<<<gg, 256, 0, stream>>>(base, norms, Wg1T, Wg2T, bg1, bg2, g2b);
    main_k<<<(TOTROWS + 255) / 256, 256, 0, stream>>>(x_emb, g2b, W1T, W2T, out);
}

// Round 4
// 908.765 us; speedup vs baseline: 2.3947x; 2.3947x over previous
//
#include <hip/hip_runtime.h>
#include <hip/hip_bf16.h>
#include <math.h>

#define NNODES 50000
#define NEDGES 800000
#define NROWS  9
#define TOTROWS (NNODES * NROWS)   // 450000
#define CHUNK  150000              // rows per m1/m2 chunk (3 chunks)
#define CBLK   1172                // ceil(CHUNK/128)

typedef _Float16 f16;
typedef _Float16 f16x8 __attribute__((ext_vector_type(8)));
typedef _Float16 f16x4 __attribute__((ext_vector_type(4)));
typedef float    f32x4 __attribute__((ext_vector_type(4)));

__device__ __forceinline__ float silu(float x) { return x / (1.0f + __expf(-x)); }

__device__ __forceinline__ f16x8 zero8() {
    f16x8 v;
    #pragma unroll
    for (int i = 0; i < 8; ++i) v[i] = (f16)0.0f;
    return v;
}

// ---------------------------------------------------------------------------
// Weight transpose + f16 convert. Dest layouts: [out_col][k] (K-contiguous).
// ---------------------------------------------------------------------------
__global__ __launch_bounds__(256) void wprep_k(
    const float* __restrict__ W1, const float* __restrict__ W2,
    const float* __restrict__ Wg1, const float* __restrict__ Wg2,
    f16* __restrict__ W1T, f16* __restrict__ W2T,
    f16* __restrict__ Wg1T, f16* __restrict__ Wg2T)
{
    int i = blockIdx.x * 256 + threadIdx.x;
    if (i < 32768) {  // W1T[n=256][k=128]
        int n = i >> 7, k = i & 127;
        W1T[i] = (f16)W1[k * 256 + n];
    }
    if (i < 32768) {  // W2T[s=128][k=256]
        int s = i >> 8, k = i & 255;
        W2T[i] = (f16)W2[k * 128 + s];
    }
    if (i < 393216) { // Wg1T[l][h=256][k=512]
        int l = i >> 17, r = i & 131071;
        int h = r >> 9, k = r & 511;
        Wg1T[i] = (f16)Wg1[l * 131072 + k * 256 + h];
    }
    if (i < 196608) { // Wg2T[l][h=256][k=256]
        int l = i >> 16, r = i & 65535;
        int h = r >> 8, k = r & 255;
        Wg2T[i] = (f16)Wg2[l * 65536 + k * 256 + h];
    }
}

// ---------------------------------------------------------------------------
// Per-node prep: x0 slot of gate base + norms (f16).
// base per node: [c_i(128) | c_ang(128) | x0(128)]
// ---------------------------------------------------------------------------
__global__ __launch_bounds__(256) void prep_k(
    const float* __restrict__ x, f16* __restrict__ base, f16* __restrict__ norms)
{
    int t = threadIdx.x;
    int node = blockIdx.x * 2 + (t >> 7);
    int c = t & 127;
    const float* xr = x + (size_t)node * (NROWS * 128) + c;
    float v0 = xr[0];
    float s1 = 0.0f, s2 = 0.0f;
    #pragma unroll
    for (int r = 1; r < 4; ++r) { float v = xr[r * 128]; s1 += v * v; }
    #pragma unroll
    for (int r = 4; r < 9; ++r) { float v = xr[r * 128]; s2 += v * v; }
    base[(size_t)node * 384 + 256 + c] = (f16)v0;
    norms[(size_t)node * 128 + c]                = (f16)fabsf(v0);
    norms[((size_t)NNODES + node) * 128 + c]     = (f16)sqrtf(s1);
    norms[((size_t)2 * NNODES + node) * 128 + c] = (f16)sqrtf(s2);
}

// ---------------------------------------------------------------------------
// CSR build
// ---------------------------------------------------------------------------
__global__ __launch_bounds__(256) void hist_k(const int* __restrict__ dst, int* __restrict__ cnt)
{
    int e = blockIdx.x * 256 + threadIdx.x;
    if (e < NEDGES) atomicAdd(&cnt[dst[e]], 1);
}

__global__ __launch_bounds__(1024) void scan_k(const int* __restrict__ cnt, int* __restrict__ row_start)
{
    __shared__ int part[1024];
    int t = threadIdx.x;
    int lo = t * 49, hi = min(lo + 49, NNODES);
    int s = 0;
    for (int i = lo; i < hi; ++i) s += cnt[i];
    part[t] = s;
    __syncthreads();
    for (int off = 1; off < 1024; off <<= 1) {
        int v = (t >= off) ? part[t - off] : 0;
        __syncthreads();
        part[t] += v;
        __syncthreads();
    }
    int run = part[t] - s;
    for (int i = lo; i < hi; ++i) { row_start[i] = run; run += cnt[i]; }
}

__global__ __launch_bounds__(256) void fill_k(
    const int* __restrict__ dst, const int* __restrict__ row_start,
    int* __restrict__ cur, int* __restrict__ eids)
{
    int e = blockIdx.x * 256 + threadIdx.x;
    if (e >= NEDGES) return;
    int d = dst[e];
    int p = atomicAdd(&cur[d], 1);
    eids[row_start[d] + p] = e;
}

// ---------------------------------------------------------------------------
// Gather means: wave per node, 2 edges in flight (32 lanes x float4 each).
// ---------------------------------------------------------------------------
__global__ __launch_bounds__(256) void gather_k(
    const float* __restrict__ t_ij, const float* __restrict__ a_ij,
    const int* __restrict__ row_start, const int* __restrict__ cnt,
    const int* __restrict__ eids, f16* __restrict__ base)
{
    int wv = threadIdx.x >> 6, ln = threadIdx.x & 63;
    int node = blockIdx.x * 4 + wv;
    int rs = row_start[node];
    int n  = cnt[node];
    int half = ln >> 5, q = ln & 31;
    float4 tc = {0,0,0,0}, ac = {0,0,0,0};
    for (int i = half; i < n; i += 2) {
        int e = eids[rs + i];
        float4 tv = ((const float4*)t_ij)[(size_t)e * 32 + q];
        float4 av = ((const float4*)a_ij)[(size_t)e * 32 + q];
        tc.x += tv.x; tc.y += tv.y; tc.z += tv.z; tc.w += tv.w;
        ac.x += av.x; ac.y += av.y; ac.z += av.z; ac.w += av.w;
    }
    tc.x += __shfl_xor(tc.x, 32); tc.y += __shfl_xor(tc.y, 32);
    tc.z += __shfl_xor(tc.z, 32); tc.w += __shfl_xor(tc.w, 32);
    ac.x += __shfl_xor(ac.x, 32); ac.y += __shfl_xor(ac.y, 32);
    ac.z += __shfl_xor(ac.z, 32); ac.w += __shfl_xor(ac.w, 32);
    float inv = 1.0f / (float)(n > 0 ? n : 1);
    if (half == 0) {
        f16x4 v;
        v[0] = (f16)(tc.x * inv); v[1] = (f16)(tc.y * inv);
        v[2] = (f16)(tc.z * inv); v[3] = (f16)(tc.w * inv);
        *(f16x4*)(base + (size_t)node * 384 + q * 4) = v;
    } else {
        f16x4 v;
        v[0] = (f16)(ac.x * inv); v[1] = (f16)(ac.y * inv);
        v[2] = (f16)(ac.z * inv); v[3] = (f16)(ac.w * inv);
        *(f16x4*)(base + (size_t)node * 384 + 128 + q * 4) = v;
    }
}

// ---------------------------------------------------------------------------
// Gate MLP, one l per blockIdx.y. 128 nodes/block, 512 threads (8 waves).
// B slabs streamed through 64KB XOR-swizzled LDS; g1 in 64KB swizzled LDS.
// Swizzle: 16B granule g at row r lives at g ^ (r & 7).
// ---------------------------------------------------------------------------
__global__ __launch_bounds__(512, 1) void gate_k(
    const f16* __restrict__ base, const f16* __restrict__ norms,
    const f16* __restrict__ Wg1T, const f16* __restrict__ Wg2T,
    const float* __restrict__ bg1, const float* __restrict__ bg2,
    f16* __restrict__ g2out)
{
    const int l  = blockIdx.y;
    const int n0 = blockIdx.x * 128;
    const int t  = threadIdx.x;
    const int wv = t >> 6, ln = t & 63;
    const int col0 = ln & 15, kq = ln >> 4;

    __shared__ f16 bs[256 * 128];    // [n=256][k-slab=128], swizzled, 64KB
    __shared__ f16 g1l[128 * 256];   // [node-row=128][h=256], swizzled, 64KB

    const int anode = n0 + wv * 16 + col0;
    const bool aok = anode < NNODES;

    f32x4 acc[16];
    #pragma unroll
    for (int nt = 0; nt < 16; ++nt) {
        float b = bg1[l * 256 + nt * 16 + col0];
        f32x4 v = {b, b, b, b};
        acc[nt] = v;
    }

    const f16* wg1 = Wg1T + (size_t)l * 131072;
    #pragma unroll
    for (int slab = 0; slab < 4; ++slab) {
        // stage B slab: 256 rows x 128 k (16 granules of 8 f16 per row)
        #pragma unroll
        for (int it = 0; it < 8; ++it) {
            int idx = t + 512 * it;
            int row = idx >> 4, g = idx & 15;
            *(f16x8*)&bs[row * 128 + (g ^ (row & 7)) * 8] =
                *(const f16x8*)(wg1 + (size_t)row * 512 + slab * 128 + g * 8);
        }
        __syncthreads();
        const f16* asrc;
        if (slab == 0)      asrc = base  + (size_t)anode * 384;
        else if (slab == 1) asrc = base  + (size_t)anode * 384 + 128;
        else if (slab == 2) asrc = norms + ((size_t)l * NNODES + anode) * 128;
        else                asrc = base  + (size_t)anode * 384 + 256;
        #pragma unroll
        for (int ks = 0; ks < 4; ++ks) {
            f16x8 a = zero8();
            if (aok) a = *(const f16x8*)(asrc + ks * 32 + kq * 8);
            #pragma unroll
            for (int nt = 0; nt < 16; ++nt) {
                int row = nt * 16 + col0;
                int g = (ks * 4 + kq) ^ (row & 7);
                f16x8 b = *(const f16x8*)&bs[row * 128 + g * 8];
                acc[nt] = __builtin_amdgcn_mfma_f32_16x16x32_f16(a, b, acc[nt], 0, 0, 0);
            }
        }
        __syncthreads();
    }

    // g1 = silu(acc) -> swizzled LDS (wave-local rows)
    #pragma unroll
    for (int nt = 0; nt < 16; ++nt)
        #pragma unroll
        for (int j = 0; j < 4; ++j) {
            int row = wv * 16 + kq * 4 + j;
            int col = nt * 16 + col0;
            int g = (col >> 3) ^ (row & 7);
            g1l[row * 256 + g * 8 + (col & 7)] = (f16)silu(acc[nt][j]);
        }

    f32x4 acc2[16];
    #pragma unroll
    for (int nt = 0; nt < 16; ++nt) {
        float b = bg2[l * 256 + nt * 16 + col0];
        f32x4 v = {b, b, b, b};
        acc2[nt] = v;
    }
    const f16* wg2 = Wg2T + (size_t)l * 65536;
    #pragma unroll
    for (int slab = 0; slab < 2; ++slab) {
        #pragma unroll
        for (int it = 0; it < 8; ++it) {
            int idx = t + 512 * it;
            int row = idx >> 4, g = idx & 15;
            *(f16x8*)&bs[row * 128 + (g ^ (row & 7)) * 8] =
                *(const f16x8*)(wg2 + (size_t)row * 256 + slab * 128 + g * 8);
        }
        __syncthreads();
        #pragma unroll
        for (int ks = 0; ks < 4; ++ks) {
            int arow = wv * 16 + col0;
            int ag = (slab * 16 + ks * 4 + kq) ^ (arow & 7);
            f16x8 a = *(const f16x8*)&g1l[arow * 256 + ag * 8];
            #pragma unroll
            for (int nt = 0; nt < 16; ++nt) {
                int row = nt * 16 + col0;
                int g = (ks * 4 + kq) ^ (row & 7);
                f16x8 b = *(const f16x8*)&bs[row * 128 + g * 8];
                acc2[nt] = __builtin_amdgcn_mfma_f32_16x16x32_f16(a, b, acc2[nt], 0, 0, 0);
            }
        }
        __syncthreads();
    }

    // g2 = silu(acc2) -> g1l (reuse), then coalesced swizzle-aware copy out
    #pragma unroll
    for (int nt = 0; nt < 16; ++nt)
        #pragma unroll
        for (int j = 0; j < 4; ++j) {
            int row = wv * 16 + kq * 4 + j;
            int col = nt * 16 + col0;
            int g = (col >> 3) ^ (row & 7);
            g1l[row * 256 + g * 8 + (col & 7)] = (f16)silu(acc2[nt][j]);
        }
    __syncthreads();
    #pragma unroll
    for (int it = 0; it < 8; ++it) {
        int idx = t + 512 * it;          // 4096 granules
        int row = idx >> 5, g = idx & 31;
        int node = n0 + row;
        if (node < NNODES) {
            f16x8 v = *(const f16x8*)&g1l[row * 256 + (g ^ (row & 7)) * 8];
            *(f16x8*)(g2out + ((size_t)l * NNODES + node) * 256 + g * 8) = v;
        }
    }
}

// ---------------------------------------------------------------------------
// m1: h = x @ W1 (f32->f16 A direct from global, W1T in LDS), gate, -> hbuf f16
// 128 rows/block, 512 threads (8 waves), W1T LDS-resident (padded, 2-way max).
// ---------------------------------------------------------------------------
__global__ __launch_bounds__(512, 4) void m1_k(
    const float* __restrict__ x, const f16* __restrict__ g2,
    const f16* __restrict__ W1T, f16* __restrict__ hbuf, int row0)
{
    const int t  = threadIdx.x;
    const int wv = t >> 6, ln = t & 63;
    const int col0 = ln & 15, kq = ln >> 4;
    const int r0 = row0 + blockIdx.x * 128;

    __shared__ f16 w[256][136];   // [n=256][k=128] pad 8 -> stride 68 dw (2-way max)
    #pragma unroll
    for (int it = 0; it < 8; ++it) {
        int idx = t + 512 * it;          // 4096 granules of 8
        int row = idx >> 4, g = idx & 15;
        *(f16x8*)&w[row][g * 8] = *(const f16x8*)(W1T + (size_t)row * 128 + g * 8);
    }
    __syncthreads();

    const int arow = r0 + wv * 16 + col0;
    const bool aok = arow < TOTROWS;
    const float* asrc = x + (size_t)arow * 128;

    f32x4 acc[16];
    #pragma unroll
    for (int nt = 0; nt < 16; ++nt) { f32x4 z = {0,0,0,0}; acc[nt] = z; }
    #pragma unroll
    for (int ks = 0; ks < 4; ++ks) {
        f16x8 a = zero8();
        if (aok) {
            float4 f0 = *(const float4*)(asrc + ks * 32 + kq * 8);
            float4 f1 = *(const float4*)(asrc + ks * 32 + kq * 8 + 4);
            a[0] = (f16)f0.x; a[1] = (f16)f0.y; a[2] = (f16)f0.z; a[3] = (f16)f0.w;
            a[4] = (f16)f1.x; a[5] = (f16)f1.y; a[6] = (f16)f1.z; a[7] = (f16)f1.w;
        }
        #pragma unroll
        for (int nt = 0; nt < 16; ++nt) {
            f16x8 b = *(const f16x8*)&w[nt * 16 + col0][ks * 32 + kq * 8];
            acc[nt] = __builtin_amdgcn_mfma_f32_16x16x32_f16(a, b, acc[nt], 0, 0, 0);
        }
    }

    // epilogue: gate from global (L2-hot rows) and store gated h as f16
    #pragma unroll
    for (int j = 0; j < 4; ++j) {
        int gr = r0 + wv * 16 + kq * 4 + j;
        if (gr < TOTROWS) {
            int node = gr / 9;
            int p = gr - node * 9;
            int lsel = (p > 0) + (p > 3);
            const f16* grow = g2 + ((size_t)lsel * NNODES + node) * 256;
            f16* hrow = hbuf + (size_t)(gr - row0) * 256;
            #pragma unroll
            for (int nt = 0; nt < 16; ++nt) {
                float h = acc[nt][j];
                if (p == 0) h = silu(h);
                float gv = (float)grow[nt * 16 + col0];
                hrow[nt * 16 + col0] = (f16)(h * gv);
            }
        }
    }
}

// ---------------------------------------------------------------------------
// m2: out = hbuf @ W2 (A f16 direct from global, W2T in LDS), f32 out.
// ---------------------------------------------------------------------------
__global__ __launch_bounds__(512, 4) void m2_k(
    const f16* __restrict__ hbuf, const f16* __restrict__ W2T,
    float* __restrict__ out, int row0)
{
    const int t  = threadIdx.x;
    const int wv = t >> 6, ln = t & 63;
    const int col0 = ln & 15, kq = ln >> 4;
    const int r0 = row0 + blockIdx.x * 128;

    __shared__ f16 w[128][264];   // [s=128][k=256] pad 8 -> stride 132 dw (2-way max)
    #pragma unroll
    for (int it = 0; it < 8; ++it) {
        int idx = t + 512 * it;          // 4096 granules of 8
        int row = idx >> 5, g = idx & 31;
        *(f16x8*)&w[row][g * 8] = *(const f16x8*)(W2T + (size_t)row * 256 + g * 8);
    }
    __syncthreads();

    const int arow = r0 + wv * 16 + col0;
    const bool aok = arow < TOTROWS;
    const f16* asrc = hbuf + (size_t)(arow - row0) * 256;

    f32x4 acc[8];
    #pragma unroll
    for (int nt = 0; nt < 8; ++nt) { f32x4 z = {0,0,0,0}; acc[nt] = z; }
    #pragma unroll
    for (int ks = 0; ks < 8; ++ks) {
        f16x8 a = zero8();
        if (aok) a = *(const f16x8*)(asrc + ks * 32 + kq * 8);
        #pragma unroll
        for (int nt = 0; nt < 8; ++nt) {
            f16x8 b = *(const f16x8*)&w[nt * 16 + col0][ks * 32 + kq * 8];
            acc[nt] = __builtin_amdgcn_mfma_f32_16x16x32_f16(a, b, acc[nt], 0, 0, 0);
        }
    }
    #pragma unroll
    for (int j = 0; j < 4; ++j) {
        int gr = r0 + wv * 16 + kq * 4 + j;
        if (gr < TOTROWS) {
            #pragma unroll
            for (int nt = 0; nt < 8; ++nt)
                out[(size_t)gr * 128 + nt * 16 + col0] = acc[j < 4 ? nt : nt][j];
        }
    }
}

// ---------------------------------------------------------------------------
extern "C" void kernel_launch(void* const* d_in, const int* in_sizes, int n_in,
                              void* d_out, int out_size, void* d_ws, size_t ws_size,
                              hipStream_t stream) {
    const float* x_emb = (const float*)d_in[0];
    const float* t_ij  = (const float*)d_in[1];
    const float* a_ij  = (const float*)d_in[2];
    const int*   eidx  = (const int*)d_in[3];
    const float* W1  = (const float*)d_in[4];
    const float* W2  = (const float*)d_in[5];
    const float* Wg1 = (const float*)d_in[6];
    const float* bg1 = (const float*)d_in[7];
    const float* Wg2 = (const float*)d_in[8];
    const float* bg2 = (const float*)d_in[9];
    float* out = (float*)d_out;
    const int* dst = eidx + NEDGES;

    // ws layout; hbuf aliases [eids|base|norms] (dead before m1/m2 phase)
    char* p = (char*)d_ws;
    int* cnt       = (int*)p;                 p += (size_t)NNODES * 4;
    int* cur       = (int*)p;                 p += (size_t)NNODES * 4;
    int* row_start = (int*)p;                 p += (size_t)(NNODES + 16) * 4;
    f16* hbuf      = (f16*)p;                 // aliases the next three buffers
    int* eids      = (int*)p;                 p += (size_t)NEDGES * 4;
    f16* base      = (f16*)p;                 p += (size_t)NNODES * 384 * 2;
    f16* norms     = (f16*)p;                 p += (size_t)3 * NNODES * 128 * 2;
    f16* g2b       = (f16*)p;                 p += (size_t)3 * NNODES * 256 * 2;
    f16* W1T       = (f16*)p;                 p += (size_t)32768 * 2;
    f16* W2T       = (f16*)p;                 p += (size_t)32768 * 2;
    f16* Wg1T      = (f16*)p;                 p += (size_t)393216 * 2;
    f16* Wg2T      = (f16*)p;                 p += (size_t)196608 * 2;

    hipMemsetAsync(cnt, 0, (size_t)2 * NNODES * 4, stream);  // cnt + cur

    wprep_k<<<1536, 256, 0, stream>>>(W1, W2, Wg1, Wg2, W1T, W2T, Wg1T, Wg2T);
    prep_k<<<NNODES / 2, 256, 0, stream>>>(x_emb, base, norms);
    hist_k<<<NEDGES / 256, 256, 0, stream>>>(dst, cnt);
    scan_k<<<1, 1024, 0, stream>>>(cnt, row_start);
    fill_k<<<NEDGES / 256, 256, 0, stream>>>(dst, row_start, cur, eids);
    gather_k<<<NNODES / 4, 256, 0, stream>>>(t_ij, a_ij, row_start, cnt, eids, base);
    dim3 gg((NNODES + 127) / 128, 3);
    gate_k<<<gg, 512, 0, stream>>>(base, norms, Wg1T, Wg2T, bg1, bg2, g2b);
    for (int c = 0; c < 3; ++c) {
        int row0 = c * CHUNK;
        m1_k<<<CBLK, 512, 0, stream>>>(x_emb, g2b, W1T, hbuf, row0);
        m2_k<<<CBLK, 512, 0, stream>>>(hbuf, W2T, out, row0);
    }
}

// Round 5
// 784.978 us; speedup vs baseline: 2.7724x; 1.1577x over previous
//
#include <hip/hip_runtime.h>
#include <hip/hip_bf16.h>
#include <math.h>

#define NNODES 50000
#define NEDGES 800000
#define NROWS  9
#define TOTROWS (NNODES * NROWS)   // 450000
#define CHUNK  150000              // rows per m1/m2 chunk (3 chunks)
#define CBLK   1172                // ceil(CHUNK/128)

typedef _Float16 f16;
typedef _Float16 f16x8 __attribute__((ext_vector_type(8)));
typedef _Float16 f16x4 __attribute__((ext_vector_type(4)));
typedef float    f32x4 __attribute__((ext_vector_type(4)));

__device__ __forceinline__ float silu(float x) { return x / (1.0f + __expf(-x)); }

__device__ __forceinline__ f16x8 zero8() {
    f16x8 v;
    #pragma unroll
    for (int i = 0; i < 8; ++i) v[i] = (f16)0.0f;
    return v;
}

// ---------------------------------------------------------------------------
// Weight transpose + f16 convert. Dest layouts: [out_col][k] (K-contiguous).
// ---------------------------------------------------------------------------
__global__ __launch_bounds__(256) void wprep_k(
    const float* __restrict__ W1, const float* __restrict__ W2,
    const float* __restrict__ Wg1, const float* __restrict__ Wg2,
    f16* __restrict__ W1T, f16* __restrict__ W2T,
    f16* __restrict__ Wg1T, f16* __restrict__ Wg2T)
{
    int i = blockIdx.x * 256 + threadIdx.x;
    if (i < 32768) {  // W1T[n=256][k=128]
        int n = i >> 7, k = i & 127;
        W1T[i] = (f16)W1[k * 256 + n];
    }
    if (i < 32768) {  // W2T[s=128][k=256]
        int s = i >> 8, k = i & 255;
        W2T[i] = (f16)W2[k * 128 + s];
    }
    if (i < 393216) { // Wg1T[l][h=256][k=512]
        int l = i >> 17, r = i & 131071;
        int h = r >> 9, k = r & 511;
        Wg1T[i] = (f16)Wg1[l * 131072 + k * 256 + h];
    }
    if (i < 196608) { // Wg2T[l][h=256][k=256]
        int l = i >> 16, r = i & 65535;
        int h = r >> 8, k = r & 255;
        Wg2T[i] = (f16)Wg2[l * 65536 + k * 256 + h];
    }
}

// ---------------------------------------------------------------------------
// Per-node prep, vectorized: x0 slot of gate base + norms (f16).
// base per node: [c_i(128) | c_ang(128) | x0(128)]
// ---------------------------------------------------------------------------
__global__ __launch_bounds__(256) void prep_k(
    const float* __restrict__ x, f16* __restrict__ base, f16* __restrict__ norms)
{
    int t = threadIdx.x;
    int node = blockIdx.x * 8 + (t >> 5);
    int c4 = (t & 31) * 4;
    const float* xr = x + (size_t)node * (NROWS * 128) + c4;
    f32x4 v0 = *(const f32x4*)xr;
    f32x4 s1 = {0,0,0,0}, s2 = {0,0,0,0};
    #pragma unroll
    for (int r = 1; r < 4; ++r) { f32x4 v = *(const f32x4*)(xr + r * 128); s1 += v * v; }
    #pragma unroll
    for (int r = 4; r < 9; ++r) { f32x4 v = *(const f32x4*)(xr + r * 128); s2 += v * v; }
    f16x4 b0, n0v, n1v, n2v;
    #pragma unroll
    for (int i = 0; i < 4; ++i) {
        b0[i]  = (f16)v0[i];
        n0v[i] = (f16)fabsf(v0[i]);
        n1v[i] = (f16)sqrtf(s1[i]);
        n2v[i] = (f16)sqrtf(s2[i]);
    }
    *(f16x4*)(base + (size_t)node * 384 + 256 + c4) = b0;
    *(f16x4*)(norms + (size_t)node * 128 + c4) = n0v;
    *(f16x4*)(norms + ((size_t)NNODES + node) * 128 + c4) = n1v;
    *(f16x4*)(norms + ((size_t)2 * NNODES + node) * 128 + c4) = n2v;
}

// ---------------------------------------------------------------------------
// CSR build
// ---------------------------------------------------------------------------
__global__ __launch_bounds__(256) void hist_k(const int* __restrict__ dst, int* __restrict__ cnt)
{
    int e = blockIdx.x * 256 + threadIdx.x;
    if (e < NEDGES) atomicAdd(&cnt[dst[e]], 1);
}

__global__ __launch_bounds__(1024) void scan_k(const int* __restrict__ cnt, int* __restrict__ row_start)
{
    __shared__ int part[1024];
    int t = threadIdx.x;
    int lo = t * 49, hi = min(lo + 49, NNODES);
    int s = 0;
    for (int i = lo; i < hi; ++i) s += cnt[i];
    part[t] = s;
    __syncthreads();
    for (int off = 1; off < 1024; off <<= 1) {
        int v = (t >= off) ? part[t - off] : 0;
        __syncthreads();
        part[t] += v;
        __syncthreads();
    }
    int run = part[t] - s;
    for (int i = lo; i < hi; ++i) { row_start[i] = run; run += cnt[i]; }
}

__global__ __launch_bounds__(256) void fill_k(
    const int* __restrict__ dst, const int* __restrict__ row_start,
    int* __restrict__ cur, int* __restrict__ eids)
{
    int e = blockIdx.x * 256 + threadIdx.x;
    if (e >= NEDGES) return;
    int d = dst[e];
    int p = atomicAdd(&cur[d], 1);
    eids[row_start[d] + p] = e;
}

// ---------------------------------------------------------------------------
// Gather means: wave per node, 4 edges in flight (16 lanes x 2xf32x4 each).
// ---------------------------------------------------------------------------
__global__ __launch_bounds__(256) void gather_k(
    const float* __restrict__ t_ij, const float* __restrict__ a_ij,
    const int* __restrict__ row_start, const int* __restrict__ cnt,
    const int* __restrict__ eids, f16* __restrict__ base)
{
    int wv = threadIdx.x >> 6, ln = threadIdx.x & 63;
    int node = blockIdx.x * 4 + wv;
    int rs = row_start[node];
    int n  = cnt[node];
    int qw = ln >> 4, q = ln & 15;
    f32x4 tc0 = {0,0,0,0}, tc1 = {0,0,0,0}, ac0 = {0,0,0,0}, ac1 = {0,0,0,0};
    for (int i = qw; i < n; i += 4) {
        int e = eids[rs + i];
        const float* tr = t_ij + (size_t)e * 128 + q * 8;
        const float* ar = a_ij + (size_t)e * 128 + q * 8;
        f32x4 t0 = *(const f32x4*)tr;
        f32x4 t1 = *(const f32x4*)(tr + 4);
        f32x4 a0 = *(const f32x4*)ar;
        f32x4 a1 = *(const f32x4*)(ar + 4);
        tc0 += t0; tc1 += t1; ac0 += a0; ac1 += a1;
    }
    #pragma unroll
    for (int m = 16; m <= 32; m <<= 1) {
        #pragma unroll
        for (int i = 0; i < 4; ++i) {
            tc0[i] += __shfl_xor(tc0[i], m);
            tc1[i] += __shfl_xor(tc1[i], m);
            ac0[i] += __shfl_xor(ac0[i], m);
            ac1[i] += __shfl_xor(ac1[i], m);
        }
    }
    float inv = 1.0f / (float)(n > 0 ? n : 1);
    if (qw == 0) {          // c_i channels q*8..q*8+7
        f16x8 v;
        #pragma unroll
        for (int i = 0; i < 4; ++i) {
            v[i]     = (f16)(tc0[i] * inv);
            v[4 + i] = (f16)(tc1[i] * inv);
        }
        *(f16x8*)(base + (size_t)node * 384 + q * 8) = v;
    } else if (qw == 1) {   // c_ang
        f16x8 v;
        #pragma unroll
        for (int i = 0; i < 4; ++i) {
            v[i]     = (f16)(ac0[i] * inv);
            v[4 + i] = (f16)(ac1[i] * inv);
        }
        *(f16x8*)(base + (size_t)node * 384 + 128 + q * 8) = v;
    }
}

// ---------------------------------------------------------------------------
// Gate MLP, one l per blockIdx.y. 64 nodes/block, 256 threads (4 waves).
// B streamed through 20KB padded LDS (k=32 slabs); g1 in 32KB swizzled LDS.
// 52KB LDS -> 3 blocks/CU (12 waves).
// ---------------------------------------------------------------------------
__global__ __launch_bounds__(256, 3) void gate_k(
    const f16* __restrict__ base, const f16* __restrict__ norms,
    const f16* __restrict__ Wg1T, const f16* __restrict__ Wg2T,
    const float* __restrict__ bg1, const float* __restrict__ bg2,
    f16* __restrict__ g2out)
{
    const int l  = blockIdx.y;
    const int n0 = blockIdx.x * 64;
    const int t  = threadIdx.x;
    const int wv = t >> 6, ln = t & 63;
    const int col0 = ln & 15, kq = ln >> 4;

    __shared__ f16 bs[256][40];      // [n=256][k=32] pad->40 (2-way max), 20KB
    __shared__ f16 g1l[64 * 256];    // swizzled, 32KB

    const int anode = n0 + wv * 16 + col0;
    const bool aok = anode < NNODES;

    f32x4 acc[16];
    #pragma unroll
    for (int nt = 0; nt < 16; ++nt) {
        float b = bg1[l * 256 + nt * 16 + col0];
        f32x4 v = {b, b, b, b};
        acc[nt] = v;
    }

    const f16* wg1 = Wg1T + (size_t)l * 131072;
    #pragma unroll
    for (int slab = 0; slab < 16; ++slab) {
        // stage B slab: 256 rows x 32 k  (1024 granules / 256 thr = 4 each)
        #pragma unroll
        for (int it = 0; it < 4; ++it) {
            int idx = t + 256 * it;
            int row = idx >> 2, g = idx & 3;
            *(f16x8*)&bs[row][g * 8] =
                *(const f16x8*)(wg1 + (size_t)row * 512 + slab * 32 + g * 8);
        }
        __syncthreads();
        const f16* asrc;
        if (slab < 8)       asrc = base  + (size_t)anode * 384 + slab * 32;
        else if (slab < 12) asrc = norms + ((size_t)l * NNODES + anode) * 128 + (slab - 8) * 32;
        else                asrc = base  + (size_t)anode * 384 + 256 + (slab - 12) * 32;
        f16x8 a = zero8();
        if (aok) a = *(const f16x8*)(asrc + kq * 8);
        #pragma unroll
        for (int nt = 0; nt < 16; ++nt) {
            f16x8 b = *(const f16x8*)&bs[nt * 16 + col0][kq * 8];
            acc[nt] = __builtin_amdgcn_mfma_f32_16x16x32_f16(a, b, acc[nt], 0, 0, 0);
        }
        __syncthreads();
    }

    // g1 = silu(acc) -> swizzled LDS (wave-local rows)
    #pragma unroll
    for (int nt = 0; nt < 16; ++nt)
        #pragma unroll
        for (int j = 0; j < 4; ++j) {
            int row = wv * 16 + kq * 4 + j;
            int col = nt * 16 + col0;
            int g = (col >> 3) ^ (row & 7);
            g1l[row * 256 + g * 8 + (col & 7)] = (f16)silu(acc[nt][j]);
        }

    f32x4 acc2[16];
    #pragma unroll
    for (int nt = 0; nt < 16; ++nt) {
        float b = bg2[l * 256 + nt * 16 + col0];
        f32x4 v = {b, b, b, b};
        acc2[nt] = v;
    }
    const f16* wg2 = Wg2T + (size_t)l * 65536;
    #pragma unroll
    for (int slab = 0; slab < 8; ++slab) {
        #pragma unroll
        for (int it = 0; it < 4; ++it) {
            int idx = t + 256 * it;
            int row = idx >> 2, g = idx & 3;
            *(f16x8*)&bs[row][g * 8] =
                *(const f16x8*)(wg2 + (size_t)row * 256 + slab * 32 + g * 8);
        }
        __syncthreads();
        int arow = wv * 16 + col0;
        int gk = slab * 4 + kq;                     // global k-granule 0..31
        f16x8 a = *(const f16x8*)&g1l[arow * 256 + (gk ^ (arow & 7)) * 8];
        #pragma unroll
        for (int nt = 0; nt < 16; ++nt) {
            f16x8 b = *(const f16x8*)&bs[nt * 16 + col0][kq * 8];
            acc2[nt] = __builtin_amdgcn_mfma_f32_16x16x32_f16(a, b, acc2[nt], 0, 0, 0);
        }
        __syncthreads();
    }

    // g2 = silu(acc2) -> g1l (reuse), then coalesced swizzle-aware copy out
    #pragma unroll
    for (int nt = 0; nt < 16; ++nt)
        #pragma unroll
        for (int j = 0; j < 4; ++j) {
            int row = wv * 16 + kq * 4 + j;
            int col = nt * 16 + col0;
            int g = (col >> 3) ^ (row & 7);
            g1l[row * 256 + g * 8 + (col & 7)] = (f16)silu(acc2[nt][j]);
        }
    __syncthreads();
    #pragma unroll
    for (int it = 0; it < 8; ++it) {
        int idx = t + 256 * it;          // 2048 granules
        int row = idx >> 5, g = idx & 31;
        int node = n0 + row;
        if (node < NNODES) {
            f16x8 v = *(const f16x8*)&g1l[row * 256 + (g ^ (row & 7)) * 8];
            *(f16x8*)(g2out + ((size_t)l * NNODES + node) * 256 + g * 8) = v;
        }
    }
}

// ---------------------------------------------------------------------------
// m1: h = x @ W1 (A direct from global f32->f16, W1T in LDS); silu on l=0
// rows; store RAW h (ungated) to hbuf f16. Gating happens in m2.
// ---------------------------------------------------------------------------
__global__ __launch_bounds__(512, 4) void m1_k(
    const float* __restrict__ x, const f16* __restrict__ W1T,
    f16* __restrict__ hbuf, int row0)
{
    const int t  = threadIdx.x;
    const int wv = t >> 6, ln = t & 63;
    const int col0 = ln & 15, kq = ln >> 4;
    const int r0 = row0 + blockIdx.x * 128;

    __shared__ f16 w[256][136];   // pad 8 -> 2-way max
    #pragma unroll
    for (int it = 0; it < 8; ++it) {
        int idx = t + 512 * it;
        int row = idx >> 4, g = idx & 15;
        *(f16x8*)&w[row][g * 8] = *(const f16x8*)(W1T + (size_t)row * 128 + g * 8);
    }
    __syncthreads();

    const int arow = r0 + wv * 16 + col0;
    const bool aok = arow < TOTROWS;
    const float* asrc = x + (size_t)arow * 128;

    f32x4 acc[16];
    #pragma unroll
    for (int nt = 0; nt < 16; ++nt) { f32x4 z = {0,0,0,0}; acc[nt] = z; }
    #pragma unroll
    for (int ks = 0; ks < 4; ++ks) {
        f16x8 a = zero8();
        if (aok) {
            float4 f0 = *(const float4*)(asrc + ks * 32 + kq * 8);
            float4 f1 = *(const float4*)(asrc + ks * 32 + kq * 8 + 4);
            a[0] = (f16)f0.x; a[1] = (f16)f0.y; a[2] = (f16)f0.z; a[3] = (f16)f0.w;
            a[4] = (f16)f1.x; a[5] = (f16)f1.y; a[6] = (f16)f1.z; a[7] = (f16)f1.w;
        }
        #pragma unroll
        for (int nt = 0; nt < 16; ++nt) {
            f16x8 b = *(const f16x8*)&w[nt * 16 + col0][ks * 32 + kq * 8];
            acc[nt] = __builtin_amdgcn_mfma_f32_16x16x32_f16(a, b, acc[nt], 0, 0, 0);
        }
    }

    #pragma unroll
    for (int j = 0; j < 4; ++j) {
        int gr = r0 + wv * 16 + kq * 4 + j;
        if (gr < TOTROWS) {
            int p = gr % 9;
            f16* hrow = hbuf + (size_t)(gr - row0) * 256;
            if (p == 0) {
                #pragma unroll
                for (int nt = 0; nt < 16; ++nt)
                    hrow[nt * 16 + col0] = (f16)silu(acc[nt][j]);
            } else {
                #pragma unroll
                for (int nt = 0; nt < 16; ++nt)
                    hrow[nt * 16 + col0] = (f16)acc[nt][j];
            }
        }
    }
}

// ---------------------------------------------------------------------------
// m2: out = (h .* g) @ W2.  Gate applied on A-fragments (coalesced g reads,
// same k-addressing as hbuf). W2T in LDS.
// ---------------------------------------------------------------------------
__global__ __launch_bounds__(512, 4) void m2_k(
    const f16* __restrict__ hbuf, const f16* __restrict__ g2,
    const f16* __restrict__ W2T, float* __restrict__ out, int row0)
{
    const int t  = threadIdx.x;
    const int wv = t >> 6, ln = t & 63;
    const int col0 = ln & 15, kq = ln >> 4;
    const int r0 = row0 + blockIdx.x * 128;

    __shared__ f16 w[128][264];   // pad 8 -> 2-way max
    #pragma unroll
    for (int it = 0; it < 8; ++it) {
        int idx = t + 512 * it;
        int row = idx >> 5, g = idx & 31;
        *(f16x8*)&w[row][g * 8] = *(const f16x8*)(W2T + (size_t)row * 256 + g * 8);
    }
    __syncthreads();

    const int arow = r0 + wv * 16 + col0;
    const bool aok = arow < TOTROWS;
    const int ar  = aok ? arow : 0;
    const int node = ar / 9;
    const int p    = ar - node * 9;
    const int lsel = (p > 0) + (p > 3);
    const f16* asrc = hbuf + (size_t)(ar - row0) * 256;
    const f16* grow = g2 + ((size_t)lsel * NNODES + node) * 256;

    f32x4 acc[8];
    #pragma unroll
    for (int nt = 0; nt < 8; ++nt) { f32x4 z = {0,0,0,0}; acc[nt] = z; }
    #pragma unroll
    for (int ks = 0; ks < 8; ++ks) {
        f16x8 a = zero8();
        if (aok) {
            f16x8 h8 = *(const f16x8*)(asrc + ks * 32 + kq * 8);
            f16x8 g8 = *(const f16x8*)(grow + ks * 32 + kq * 8);
            #pragma unroll
            for (int i = 0; i < 8; ++i)
                a[i] = (f16)((float)h8[i] * (float)g8[i]);
        }
        #pragma unroll
        for (int nt = 0; nt < 8; ++nt) {
            f16x8 b = *(const f16x8*)&w[nt * 16 + col0][ks * 32 + kq * 8];
            acc[nt] = __builtin_amdgcn_mfma_f32_16x16x32_f16(a, b, acc[nt], 0, 0, 0);
        }
    }
    #pragma unroll
    for (int j = 0; j < 4; ++j) {
        int gr = r0 + wv * 16 + kq * 4 + j;
        if (gr < TOTROWS) {
            #pragma unroll
            for (int nt = 0; nt < 8; ++nt)
                out[(size_t)gr * 128 + nt * 16 + col0] = acc[nt][j];
        }
    }
}

// ---------------------------------------------------------------------------
extern "C" void kernel_launch(void* const* d_in, const int* in_sizes, int n_in,
                              void* d_out, int out_size, void* d_ws, size_t ws_size,
                              hipStream_t stream) {
    const float* x_emb = (const float*)d_in[0];
    const float* t_ij  = (const float*)d_in[1];
    const float* a_ij  = (const float*)d_in[2];
    const int*   eidx  = (const int*)d_in[3];
    const float* W1  = (const float*)d_in[4];
    const float* W2  = (const float*)d_in[5];
    const float* Wg1 = (const float*)d_in[6];
    const float* bg1 = (const float*)d_in[7];
    const float* Wg2 = (const float*)d_in[8];
    const float* bg2 = (const float*)d_in[9];
    float* out = (float*)d_out;
    const int* dst = eidx + NEDGES;

    // ws layout; hbuf aliases [eids|base|norms] (dead before m1/m2 phase)
    char* p = (char*)d_ws;
    int* cnt       = (int*)p;                 p += (size_t)NNODES * 4;
    int* cur       = (int*)p;                 p += (size_t)NNODES * 4;
    int* row_start = (int*)p;                 p += (size_t)(NNODES + 16) * 4;
    f16* hbuf      = (f16*)p;                 // aliases the next three buffers
    int* eids      = (int*)p;                 p += (size_t)NEDGES * 4;
    f16* base      = (f16*)p;                 p += (size_t)NNODES * 384 * 2;
    f16* norms     = (f16*)p;                 p += (size_t)3 * NNODES * 128 * 2;
    f16* g2b       = (f16*)p;                 p += (size_t)3 * NNODES * 256 * 2;
    f16* W1T       = (f16*)p;                 p += (size_t)32768 * 2;
    f16* W2T       = (f16*)p;                 p += (size_t)32768 * 2;
    f16* Wg1T      = (f16*)p;                 p += (size_t)393216 * 2;
    f16* Wg2T      = (f16*)p;                 p += (size_t)196608 * 2;

    hipMemsetAsync(cnt, 0, (size_t)2 * NNODES * 4, stream);  // cnt + cur

    wprep_k<<<1536, 256, 0, stream>>>(W1, W2, Wg1, Wg2, W1T, W2T, Wg1T, Wg2T);
    prep_k<<<NNODES / 8, 256, 0, stream>>>(x_emb, base, norms);
    hist_k<<<NEDGES / 256, 256, 0, stream>>>(dst, cnt);
    scan_k<<<1, 1024, 0, stream>>>(cnt, row_start);
    fill_k<<<NEDGES / 256, 256, 0, stream>>>(dst, row_start, cur, eids);
    gather_k<<<NNODES / 4, 256, 0, stream>>>(t_ij, a_ij, row_start, cnt, eids, base);
    dim3 gg((NNODES + 63) / 64, 3);
    gate_k<<<gg, 256, 0, stream>>>(base, norms, Wg1T, Wg2T, bg1, bg2, g2b);
    for (int c = 0; c < 3; ++c) {
        int row0 = c * CHUNK;
        m1_k<<<CBLK, 512, 0, stream>>>(x_emb, W1T, hbuf, row0);
        m2_k<<<CBLK, 512, 0, stream>>>(hbuf, g2b, W2T, out, row0);
    }
}

// Round 6
// 733.515 us; speedup vs baseline: 2.9669x; 1.0702x over previous
//
#include <hip/hip_runtime.h>
#include <hip/hip_bf16.h>
#include <math.h>

#define NNODES 50000
#define NEDGES 800000
#define NROWS  9
#define TOTROWS (NNODES * NROWS)   // 450000
#define MKBLK  3516                // ceil(450000/128)

typedef _Float16 f16;
typedef _Float16 f16x8 __attribute__((ext_vector_type(8)));
typedef _Float16 f16x4 __attribute__((ext_vector_type(4)));
typedef float    f32x4 __attribute__((ext_vector_type(4)));

__device__ __forceinline__ float silu(float x) { return x / (1.0f + __expf(-x)); }

__device__ __forceinline__ f16x8 zero8() {
    f16x8 v;
    #pragma unroll
    for (int i = 0; i < 8; ++i) v[i] = (f16)0.0f;
    return v;
}

// ---------------------------------------------------------------------------
// Weight transpose + f16 convert. Dest layouts: [out_col][k] (K-contiguous).
// ---------------------------------------------------------------------------
__global__ __launch_bounds__(256) void wprep_k(
    const float* __restrict__ W1, const float* __restrict__ W2,
    const float* __restrict__ Wg1, const float* __restrict__ Wg2,
    f16* __restrict__ W1T, f16* __restrict__ W2T,
    f16* __restrict__ Wg1T, f16* __restrict__ Wg2T)
{
    int i = blockIdx.x * 256 + threadIdx.x;
    if (i < 32768) {  // W1T[n=256][k=128]
        int n = i >> 7, k = i & 127;
        W1T[i] = (f16)W1[k * 256 + n];
    }
    if (i < 32768) {  // W2T[s=128][k=256]
        int s = i >> 8, k = i & 255;
        W2T[i] = (f16)W2[k * 128 + s];
    }
    if (i < 393216) { // Wg1T[l][h=256][k=512]
        int l = i >> 17, r = i & 131071;
        int h = r >> 9, k = r & 511;
        Wg1T[i] = (f16)Wg1[l * 131072 + k * 256 + h];
    }
    if (i < 196608) { // Wg2T[l][h=256][k=256]
        int l = i >> 16, r = i & 65535;
        int h = r >> 8, k = r & 255;
        Wg2T[i] = (f16)Wg2[l * 65536 + k * 256 + h];
    }
}

// ---------------------------------------------------------------------------
// Per-node prep, vectorized: x0 slot of gate base + norms (f16).
// base per node: [c_i(128) | c_ang(128) | x0(128)]
// ---------------------------------------------------------------------------
__global__ __launch_bounds__(256) void prep_k(
    const float* __restrict__ x, f16* __restrict__ base, f16* __restrict__ norms)
{
    int t = threadIdx.x;
    int node = blockIdx.x * 8 + (t >> 5);
    int c4 = (t & 31) * 4;
    const float* xr = x + (size_t)node * (NROWS * 128) + c4;
    f32x4 v0 = *(const f32x4*)xr;
    f32x4 s1 = {0,0,0,0}, s2 = {0,0,0,0};
    #pragma unroll
    for (int r = 1; r < 4; ++r) { f32x4 v = *(const f32x4*)(xr + r * 128); s1 += v * v; }
    #pragma unroll
    for (int r = 4; r < 9; ++r) { f32x4 v = *(const f32x4*)(xr + r * 128); s2 += v * v; }
    f16x4 b0, n0v, n1v, n2v;
    #pragma unroll
    for (int i = 0; i < 4; ++i) {
        b0[i]  = (f16)v0[i];
        n0v[i] = (f16)fabsf(v0[i]);
        n1v[i] = (f16)sqrtf(s1[i]);
        n2v[i] = (f16)sqrtf(s2[i]);
    }
    *(f16x4*)(base + (size_t)node * 384 + 256 + c4) = b0;
    *(f16x4*)(norms + (size_t)node * 128 + c4) = n0v;
    *(f16x4*)(norms + ((size_t)NNODES + node) * 128 + c4) = n1v;
    *(f16x4*)(norms + ((size_t)2 * NNODES + node) * 128 + c4) = n2v;
}

// ---------------------------------------------------------------------------
// CSR build
// ---------------------------------------------------------------------------
__global__ __launch_bounds__(256) void hist_k(const int* __restrict__ dst, int* __restrict__ cnt)
{
    int e = blockIdx.x * 256 + threadIdx.x;
    if (e < NEDGES) atomicAdd(&cnt[dst[e]], 1);
}

__global__ __launch_bounds__(1024) void scan_k(const int* __restrict__ cnt, int* __restrict__ row_start)
{
    __shared__ int part[1024];
    int t = threadIdx.x;
    int lo = t * 49, hi = min(lo + 49, NNODES);
    int s = 0;
    for (int i = lo; i < hi; ++i) s += cnt[i];
    part[t] = s;
    __syncthreads();
    for (int off = 1; off < 1024; off <<= 1) {
        int v = (t >= off) ? part[t - off] : 0;
        __syncthreads();
        part[t] += v;
        __syncthreads();
    }
    int run = part[t] - s;
    for (int i = lo; i < hi; ++i) { row_start[i] = run; run += cnt[i]; }
}

__global__ __launch_bounds__(256) void fill_k(
    const int* __restrict__ dst, const int* __restrict__ row_start,
    int* __restrict__ cur, int* __restrict__ eids)
{
    int e = blockIdx.x * 256 + threadIdx.x;
    if (e >= NEDGES) return;
    int d = dst[e];
    int p = atomicAdd(&cur[d], 1);
    eids[row_start[d] + p] = e;
}

// ---------------------------------------------------------------------------
// Gather means: wave per node, 4 edges in flight (16 lanes x 2xf32x4 each).
// ---------------------------------------------------------------------------
__global__ __launch_bounds__(256) void gather_k(
    const float* __restrict__ t_ij, const float* __restrict__ a_ij,
    const int* __restrict__ row_start, const int* __restrict__ cnt,
    const int* __restrict__ eids, f16* __restrict__ base)
{
    int wv = threadIdx.x >> 6, ln = threadIdx.x & 63;
    int node = blockIdx.x * 4 + wv;
    int rs = row_start[node];
    int n  = cnt[node];
    int qw = ln >> 4, q = ln & 15;
    f32x4 tc0 = {0,0,0,0}, tc1 = {0,0,0,0}, ac0 = {0,0,0,0}, ac1 = {0,0,0,0};
    for (int i = qw; i < n; i += 4) {
        int e = eids[rs + i];
        const float* tr = t_ij + (size_t)e * 128 + q * 8;
        const float* ar = a_ij + (size_t)e * 128 + q * 8;
        f32x4 t0 = *(const f32x4*)tr;
        f32x4 t1 = *(const f32x4*)(tr + 4);
        f32x4 a0 = *(const f32x4*)ar;
        f32x4 a1 = *(const f32x4*)(ar + 4);
        tc0 += t0; tc1 += t1; ac0 += a0; ac1 += a1;
    }
    #pragma unroll
    for (int m = 16; m <= 32; m <<= 1) {
        #pragma unroll
        for (int i = 0; i < 4; ++i) {
            tc0[i] += __shfl_xor(tc0[i], m);
            tc1[i] += __shfl_xor(tc1[i], m);
            ac0[i] += __shfl_xor(ac0[i], m);
            ac1[i] += __shfl_xor(ac1[i], m);
        }
    }
    float inv = 1.0f / (float)(n > 0 ? n : 1);
    if (qw == 0) {          // c_i channels q*8..q*8+7
        f16x8 v;
        #pragma unroll
        for (int i = 0; i < 4; ++i) {
            v[i]     = (f16)(tc0[i] * inv);
            v[4 + i] = (f16)(tc1[i] * inv);
        }
        *(f16x8*)(base + (size_t)node * 384 + q * 8) = v;
    } else if (qw == 1) {   // c_ang
        f16x8 v;
        #pragma unroll
        for (int i = 0; i < 4; ++i) {
            v[i]     = (f16)(ac0[i] * inv);
            v[4 + i] = (f16)(ac1[i] * inv);
        }
        *(f16x8*)(base + (size_t)node * 384 + 128 + q * 8) = v;
    }
}

// ---------------------------------------------------------------------------
// Gate MLP, one l per blockIdx.y. 64 nodes/block, 256 threads (4 waves).
// B streamed through 20KB padded LDS (k=32 slabs); g1 in 32KB swizzled LDS.
// 52KB LDS -> 3 blocks/CU (12 waves).
// ---------------------------------------------------------------------------
__global__ __launch_bounds__(256, 3) void gate_k(
    const f16* __restrict__ base, const f16* __restrict__ norms,
    const f16* __restrict__ Wg1T, const f16* __restrict__ Wg2T,
    const float* __restrict__ bg1, const float* __restrict__ bg2,
    f16* __restrict__ g2out)
{
    const int l  = blockIdx.y;
    const int n0 = blockIdx.x * 64;
    const int t  = threadIdx.x;
    const int wv = t >> 6, ln = t & 63;
    const int col0 = ln & 15, kq = ln >> 4;

    __shared__ f16 bs[256][40];      // [n=256][k=32] pad->40 (2-way max), 20KB
    __shared__ f16 g1l[64 * 256];    // swizzled, 32KB

    const int anode = n0 + wv * 16 + col0;
    const bool aok = anode < NNODES;

    f32x4 acc[16];
    #pragma unroll
    for (int nt = 0; nt < 16; ++nt) {
        float b = bg1[l * 256 + nt * 16 + col0];
        f32x4 v = {b, b, b, b};
        acc[nt] = v;
    }

    const f16* wg1 = Wg1T + (size_t)l * 131072;
    #pragma unroll
    for (int slab = 0; slab < 16; ++slab) {
        // stage B slab: 256 rows x 32 k  (1024 granules / 256 thr = 4 each)
        #pragma unroll
        for (int it = 0; it < 4; ++it) {
            int idx = t + 256 * it;
            int row = idx >> 2, g = idx & 3;
            *(f16x8*)&bs[row][g * 8] =
                *(const f16x8*)(wg1 + (size_t)row * 512 + slab * 32 + g * 8);
        }
        __syncthreads();
        const f16* asrc;
        if (slab < 8)       asrc = base  + (size_t)anode * 384 + slab * 32;
        else if (slab < 12) asrc = norms + ((size_t)l * NNODES + anode) * 128 + (slab - 8) * 32;
        else                asrc = base  + (size_t)anode * 384 + 256 + (slab - 12) * 32;
        f16x8 a = zero8();
        if (aok) a = *(const f16x8*)(asrc + kq * 8);
        #pragma unroll
        for (int nt = 0; nt < 16; ++nt) {
            f16x8 b = *(const f16x8*)&bs[nt * 16 + col0][kq * 8];
            acc[nt] = __builtin_amdgcn_mfma_f32_16x16x32_f16(a, b, acc[nt], 0, 0, 0);
        }
        __syncthreads();
    }

    // g1 = silu(acc) -> swizzled LDS (wave-local rows)
    #pragma unroll
    for (int nt = 0; nt < 16; ++nt)
        #pragma unroll
        for (int j = 0; j < 4; ++j) {
            int row = wv * 16 + kq * 4 + j;
            int col = nt * 16 + col0;
            int g = (col >> 3) ^ (row & 7);
            g1l[row * 256 + g * 8 + (col & 7)] = (f16)silu(acc[nt][j]);
        }

    f32x4 acc2[16];
    #pragma unroll
    for (int nt = 0; nt < 16; ++nt) {
        float b = bg2[l * 256 + nt * 16 + col0];
        f32x4 v = {b, b, b, b};
        acc2[nt] = v;
    }
    const f16* wg2 = Wg2T + (size_t)l * 65536;
    #pragma unroll
    for (int slab = 0; slab < 8; ++slab) {
        #pragma unroll
        for (int it = 0; it < 4; ++it) {
            int idx = t + 256 * it;
            int row = idx >> 2, g = idx & 3;
            *(f16x8*)&bs[row][g * 8] =
                *(const f16x8*)(wg2 + (size_t)row * 256 + slab * 32 + g * 8);
        }
        __syncthreads();
        int arow = wv * 16 + col0;
        int gk = slab * 4 + kq;                     // global k-granule 0..31
        f16x8 a = *(const f16x8*)&g1l[arow * 256 + (gk ^ (arow & 7)) * 8];
        #pragma unroll
        for (int nt = 0; nt < 16; ++nt) {
            f16x8 b = *(const f16x8*)&bs[nt * 16 + col0][kq * 8];
            acc2[nt] = __builtin_amdgcn_mfma_f32_16x16x32_f16(a, b, acc2[nt], 0, 0, 0);
        }
        __syncthreads();
    }

    // g2 = silu(acc2) -> g1l (reuse), then coalesced swizzle-aware copy out
    #pragma unroll
    for (int nt = 0; nt < 16; ++nt)
        #pragma unroll
        for (int j = 0; j < 4; ++j) {
            int row = wv * 16 + kq * 4 + j;
            int col = nt * 16 + col0;
            int g = (col >> 3) ^ (row & 7);
            g1l[row * 256 + g * 8 + (col & 7)] = (f16)silu(acc2[nt][j]);
        }
    __syncthreads();
    #pragma unroll
    for (int it = 0; it < 8; ++it) {
        int idx = t + 256 * it;          // 2048 granules
        int row = idx >> 5, g = idx & 31;
        int node = n0 + row;
        if (node < NNODES) {
            f16x8 v = *(const f16x8*)&g1l[row * 256 + (g ^ (row & 7)) * 8];
            *(f16x8*)(g2out + ((size_t)l * NNODES + node) * 256 + g * 8) = v;
        }
    }
}

// ---------------------------------------------------------------------------
// mk: fused h = x@W1 -> (silu l0) -> LDS; restage W2 over W1; out = (h.*g)@W2
// 128 rows/block, 512 threads (8 waves). LDS: wmem 69.6KB (W1 [256][136],
// then W2 [128][264]) + hld 67.6KB = 137KB -> 1 block/CU, 3 barriers.
// ---------------------------------------------------------------------------
__global__ __launch_bounds__(512, 2) void mk_k(
    const float* __restrict__ x, const f16* __restrict__ g2,
    const f16* __restrict__ W1T, const f16* __restrict__ W2T,
    float* __restrict__ out)
{
    const int t  = threadIdx.x;
    const int wv = t >> 6, ln = t & 63;
    const int col0 = ln & 15, kq = ln >> 4;
    const int r0 = blockIdx.x * 128;

    __shared__ f16 wmem[34816];        // W1 view [256][136] / W2 view [128][264]
    __shared__ f16 hld[128][264];

    // ---- stage W1 ----
    #pragma unroll
    for (int it = 0; it < 8; ++it) {
        int idx = t + 512 * it;        // 4096 granules of 8
        int row = idx >> 4, g = idx & 15;
        *(f16x8*)&wmem[row * 136 + g * 8] = *(const f16x8*)(W1T + (size_t)row * 128 + g * 8);
    }
    __syncthreads();

    const int arow = r0 + wv * 16 + col0;
    const bool aok = arow < TOTROWS;
    const int ar  = aok ? arow : 0;
    const int node = ar / 9;
    const int p    = ar - node * 9;
    const int lsel = (p > 0) + (p > 3);
    const float* asrc = x + (size_t)arow * 128;
    const f16* grow = g2 + ((size_t)lsel * NNODES + node) * 256;

    // ---- GEMM1: h = x @ W1 (A direct from global, f32->f16) ----
    f32x4 acc[16];
    #pragma unroll
    for (int nt = 0; nt < 16; ++nt) { f32x4 z = {0,0,0,0}; acc[nt] = z; }
    #pragma unroll
    for (int ks = 0; ks < 4; ++ks) {
        f16x8 a = zero8();
        if (aok) {
            float4 f0 = *(const float4*)(asrc + ks * 32 + kq * 8);
            float4 f1 = *(const float4*)(asrc + ks * 32 + kq * 8 + 4);
            a[0] = (f16)f0.x; a[1] = (f16)f0.y; a[2] = (f16)f0.z; a[3] = (f16)f0.w;
            a[4] = (f16)f1.x; a[5] = (f16)f1.y; a[6] = (f16)f1.z; a[7] = (f16)f1.w;
        }
        #pragma unroll
        for (int nt = 0; nt < 16; ++nt) {
            f16x8 b = *(const f16x8*)&wmem[(nt * 16 + col0) * 136 + ks * 32 + kq * 8];
            acc[nt] = __builtin_amdgcn_mfma_f32_16x16x32_f16(a, b, acc[nt], 0, 0, 0);
        }
    }

    // ---- h (silu on l=0 rows) -> hld ----
    #pragma unroll
    for (int j = 0; j < 4; ++j) {
        int rl = wv * 16 + kq * 4 + j;
        int pj = (r0 + rl) % 9;
        if (pj == 0) {
            #pragma unroll
            for (int nt = 0; nt < 16; ++nt)
                hld[rl][nt * 16 + col0] = (f16)silu(acc[nt][j]);
        } else {
            #pragma unroll
            for (int nt = 0; nt < 16; ++nt)
                hld[rl][nt * 16 + col0] = (f16)acc[nt][j];
        }
    }
    __syncthreads();   // all waves done with W1 + h visible

    // ---- stage W2 over W1's region ----
    #pragma unroll
    for (int it = 0; it < 8; ++it) {
        int idx = t + 512 * it;        // 4096 granules of 8
        int row = idx >> 5, g = idx & 31;
        *(f16x8*)&wmem[row * 264 + g * 8] = *(const f16x8*)(W2T + (size_t)row * 256 + g * 8);
    }
    __syncthreads();

    // ---- GEMM2: out = (h .* g) @ W2; gate applied on A-fragments ----
    f32x4 acc2[8];
    #pragma unroll
    for (int nt = 0; nt < 8; ++nt) { f32x4 z = {0,0,0,0}; acc2[nt] = z; }
    #pragma unroll
    for (int ks = 0; ks < 8; ++ks) {
        f16x8 a = zero8();
        if (aok) {
            f16x8 h8 = *(const f16x8*)&hld[wv * 16 + col0][ks * 32 + kq * 8];
            f16x8 g8 = *(const f16x8*)(grow + ks * 32 + kq * 8);
            #pragma unroll
            for (int i = 0; i < 8; ++i)
                a[i] = (f16)((float)h8[i] * (float)g8[i]);
        }
        #pragma unroll
        for (int nt = 0; nt < 8; ++nt) {
            f16x8 b = *(const f16x8*)&wmem[(nt * 16 + col0) * 264 + ks * 32 + kq * 8];
            acc2[nt] = __builtin_amdgcn_mfma_f32_16x16x32_f16(a, b, acc2[nt], 0, 0, 0);
        }
    }
    #pragma unroll
    for (int j = 0; j < 4; ++j) {
        int gr = r0 + wv * 16 + kq * 4 + j;
        if (gr < TOTROWS) {
            #pragma unroll
            for (int nt = 0; nt < 8; ++nt)
                out[(size_t)gr * 128 + nt * 16 + col0] = acc2[nt][j];
        }
    }
}

// ---------------------------------------------------------------------------
extern "C" void kernel_launch(void* const* d_in, const int* in_sizes, int n_in,
                              void* d_out, int out_size, void* d_ws, size_t ws_size,
                              hipStream_t stream) {
    const float* x_emb = (const float*)d_in[0];
    const float* t_ij  = (const float*)d_in[1];
    const float* a_ij  = (const float*)d_in[2];
    const int*   eidx  = (const int*)d_in[3];
    const float* W1  = (const float*)d_in[4];
    const float* W2  = (const float*)d_in[5];
    const float* Wg1 = (const float*)d_in[6];
    const float* bg1 = (const float*)d_in[7];
    const float* Wg2 = (const float*)d_in[8];
    const float* bg2 = (const float*)d_in[9];
    float* out = (float*)d_out;
    const int* dst = eidx + NEDGES;

    char* p = (char*)d_ws;
    int* cnt       = (int*)p;                 p += (size_t)NNODES * 4;
    int* cur       = (int*)p;                 p += (size_t)NNODES * 4;
    int* row_start = (int*)p;                 p += (size_t)(NNODES + 16) * 4;
    int* eids      = (int*)p;                 p += (size_t)NEDGES * 4;
    f16* base      = (f16*)p;                 p += (size_t)NNODES * 384 * 2;
    f16* norms     = (f16*)p;                 p += (size_t)3 * NNODES * 128 * 2;
    f16* g2b       = (f16*)p;                 p += (size_t)3 * NNODES * 256 * 2;
    f16* W1T       = (f16*)p;                 p += (size_t)32768 * 2;
    f16* W2T       = (f16*)p;                 p += (size_t)32768 * 2;
    f16* Wg1T      = (f16*)p;                 p += (size_t)393216 * 2;
    f16* Wg2T      = (f16*)p;                 p += (size_t)196608 * 2;

    hipMemsetAsync(cnt, 0, (size_t)2 * NNODES * 4, stream);  // cnt + cur

    wprep_k<<<1536, 256, 0, stream>>>(W1, W2, Wg1, Wg2, W1T, W2T, Wg1T, Wg2T);
    prep_k<<<NNODES / 8, 256, 0, stream>>>(x_emb, base, norms);
    hist_k<<<NEDGES / 256, 256, 0, stream>>>(dst, cnt);
    scan_k<<<1, 1024, 0, stream>>>(cnt, row_start);
    fill_k<<<NEDGES / 256, 256, 0, stream>>>(dst, row_start, cur, eids);
    gather_k<<<NNODES / 4, 256, 0, stream>>>(t_ij, a_ij, row_start, cnt, eids, base);
    dim3 gg((NNODES + 63) / 64, 3);
    gate_k<<<gg, 256, 0, stream>>>(base, norms, Wg1T, Wg2T, bg1, bg2, g2b);
    mk_k<<<MKBLK, 512, 0, stream>>>(x_emb, g2b, W1T, W2T, out);
}

// Round 9
// 705.937 us; speedup vs baseline: 3.0828x; 1.0391x over previous
//
#include <hip/hip_runtime.h>
#include <hip/hip_bf16.h>
#include <math.h>

#define NNODES 50000
#define NEDGES 800000
#define NROWS  9
#define TOTROWS (NNODES * NROWS)   // 450000
#define MKBLK  7032                // ceil(450000/64)

typedef _Float16 f16;
typedef _Float16 f16x8 __attribute__((ext_vector_type(8)));
typedef _Float16 f16x4 __attribute__((ext_vector_type(4)));
typedef float    f32x4 __attribute__((ext_vector_type(4)));

__device__ __forceinline__ float silu(float x) { return x / (1.0f + __expf(-x)); }

__device__ __forceinline__ f16x8 zero8() {
    f16x8 v;
    #pragma unroll
    for (int i = 0; i < 8; ++i) v[i] = (f16)0.0f;
    return v;
}

// ---------------------------------------------------------------------------
// Weight transpose + f16 convert. Dest layouts: [out_col][k] (K-contiguous).
// ---------------------------------------------------------------------------
__global__ __launch_bounds__(256) void wprep_k(
    const float* __restrict__ W1, const float* __restrict__ W2,
    const float* __restrict__ Wg1, const float* __restrict__ Wg2,
    f16* __restrict__ W1T, f16* __restrict__ W2T,
    f16* __restrict__ Wg1T, f16* __restrict__ Wg2T)
{
    int i = blockIdx.x * 256 + threadIdx.x;
    if (i < 32768) {  // W1T[n=256][k=128]
        int n = i >> 7, k = i & 127;
        W1T[i] = (f16)W1[k * 256 + n];
    }
    if (i < 32768) {  // W2T[s=128][k=256]
        int s = i >> 8, k = i & 255;
        W2T[i] = (f16)W2[k * 128 + s];
    }
    if (i < 393216) { // Wg1T[l][h=256][k=512]
        int l = i >> 17, r = i & 131071;
        int h = r >> 9, k = r & 511;
        Wg1T[i] = (f16)Wg1[l * 131072 + k * 256 + h];
    }
    if (i < 196608) { // Wg2T[l][h=256][k=256]
        int l = i >> 16, r = i & 65535;
        int h = r >> 8, k = r & 255;
        Wg2T[i] = (f16)Wg2[l * 65536 + k * 256 + h];
    }
}

// ---------------------------------------------------------------------------
// Per-node prep, vectorized: x0 slot of gate base + norms (f16).
// base per node: [c_i(128) | c_ang(128) | x0(128)]
// ---------------------------------------------------------------------------
__global__ __launch_bounds__(256) void prep_k(
    const float* __restrict__ x, f16* __restrict__ base, f16* __restrict__ norms)
{
    int t = threadIdx.x;
    int node = blockIdx.x * 8 + (t >> 5);
    int c4 = (t & 31) * 4;
    const float* xr = x + (size_t)node * (NROWS * 128) + c4;
    f32x4 v0 = *(const f32x4*)xr;
    f32x4 s1 = {0,0,0,0}, s2 = {0,0,0,0};
    #pragma unroll
    for (int r = 1; r < 4; ++r) { f32x4 v = *(const f32x4*)(xr + r * 128); s1 += v * v; }
    #pragma unroll
    for (int r = 4; r < 9; ++r) { f32x4 v = *(const f32x4*)(xr + r * 128); s2 += v * v; }
    f16x4 b0, n0v, n1v, n2v;
    #pragma unroll
    for (int i = 0; i < 4; ++i) {
        b0[i]  = (f16)v0[i];
        n0v[i] = (f16)fabsf(v0[i]);
        n1v[i] = (f16)sqrtf(s1[i]);
        n2v[i] = (f16)sqrtf(s2[i]);
    }
    *(f16x4*)(base + (size_t)node * 384 + 256 + c4) = b0;
    *(f16x4*)(norms + (size_t)node * 128 + c4) = n0v;
    *(f16x4*)(norms + ((size_t)NNODES + node) * 128 + c4) = n1v;
    *(f16x4*)(norms + ((size_t)2 * NNODES + node) * 128 + c4) = n2v;
}

// ---------------------------------------------------------------------------
// CSR build
// ---------------------------------------------------------------------------
__global__ __launch_bounds__(256) void hist_k(const int* __restrict__ dst, int* __restrict__ cnt)
{
    int e = blockIdx.x * 256 + threadIdx.x;
    if (e < NEDGES) atomicAdd(&cnt[dst[e]], 1);
}

__global__ __launch_bounds__(1024) void scan_k(const int* __restrict__ cnt, int* __restrict__ row_start)
{
    __shared__ int part[1024];
    int t = threadIdx.x;
    int lo = t * 49, hi = min(lo + 49, NNODES);
    int s = 0;
    for (int i = lo; i < hi; ++i) s += cnt[i];
    part[t] = s;
    __syncthreads();
    for (int off = 1; off < 1024; off <<= 1) {
        int v = (t >= off) ? part[t - off] : 0;
        __syncthreads();
        part[t] += v;
        __syncthreads();
    }
    int run = part[t] - s;
    for (int i = lo; i < hi; ++i) { row_start[i] = run; run += cnt[i]; }
}

__global__ __launch_bounds__(256) void fill_k(
    const int* __restrict__ dst, const int* __restrict__ row_start,
    int* __restrict__ cur, int* __restrict__ eids)
{
    int e = blockIdx.x * 256 + threadIdx.x;
    if (e >= NEDGES) return;
    int d = dst[e];
    int p = atomicAdd(&cur[d], 1);
    eids[row_start[d] + p] = e;
}

// ---------------------------------------------------------------------------
// Gather means: wave per node. Coalesced eids load (64/chunk) + shfl
// broadcast with WAVE-UNIFORM control flow (shfl never under divergence);
// row loads independent (deep ILP), nontemporal.
// ---------------------------------------------------------------------------
__global__ __launch_bounds__(256) void gather_k(
    const float* __restrict__ t_ij, const float* __restrict__ a_ij,
    const int* __restrict__ row_start, const int* __restrict__ cnt,
    const int* __restrict__ eids, f16* __restrict__ base)
{
    int wv = threadIdx.x >> 6, ln = threadIdx.x & 63;
    int node = blockIdx.x * 4 + wv;
    int rs = row_start[node];
    int n  = cnt[node];
    int qw = ln >> 4, q = ln & 15;
    f32x4 tc0 = {0,0,0,0}, tc1 = {0,0,0,0}, ac0 = {0,0,0,0}, ac1 = {0,0,0,0};
    for (int b0 = 0; b0 < n; b0 += 64) {          // wave-uniform bound
        int ecnt = min(64, n - b0);
        int eid = (b0 + ln < n) ? eids[rs + b0 + ln] : 0;
        for (int i0 = 0; i0 < ecnt; i0 += 4) {    // wave-uniform bound
            int i = i0 + qw;                       // this lane's edge in group
            int e = __shfl(eid, i & 63);           // all 64 lanes execute
            if (i < ecnt) {
                const f32x4* tr = (const f32x4*)(t_ij + (size_t)e * 128 + q * 8);
                const f32x4* ar = (const f32x4*)(a_ij + (size_t)e * 128 + q * 8);
                f32x4 t0 = __builtin_nontemporal_load(tr);
                f32x4 t1 = __builtin_nontemporal_load(tr + 1);
                f32x4 a0 = __builtin_nontemporal_load(ar);
                f32x4 a1 = __builtin_nontemporal_load(ar + 1);
                tc0 += t0; tc1 += t1; ac0 += a0; ac1 += a1;
            }
        }
    }
    #pragma unroll
    for (int m = 16; m <= 32; m <<= 1) {
        #pragma unroll
        for (int i = 0; i < 4; ++i) {
            tc0[i] += __shfl_xor(tc0[i], m);
            tc1[i] += __shfl_xor(tc1[i], m);
            ac0[i] += __shfl_xor(ac0[i], m);
            ac1[i] += __shfl_xor(ac1[i], m);
        }
    }
    float inv = 1.0f / (float)(n > 0 ? n : 1);
    if (qw == 0) {          // c_i channels q*8..q*8+7
        f16x8 v;
        #pragma unroll
        for (int i = 0; i < 4; ++i) {
            v[i]     = (f16)(tc0[i] * inv);
            v[4 + i] = (f16)(tc1[i] * inv);
        }
        *(f16x8*)(base + (size_t)node * 384 + q * 8) = v;
    } else if (qw == 1) {   // c_ang
        f16x8 v;
        #pragma unroll
        for (int i = 0; i < 4; ++i) {
            v[i]     = (f16)(ac0[i] * inv);
            v[4 + i] = (f16)(ac1[i] * inv);
        }
        *(f16x8*)(base + (size_t)node * 384 + 128 + q * 8) = v;
    }
}

// ---------------------------------------------------------------------------
// Gate MLP, one l per blockIdx.y. 64 nodes/block, 256 threads (4 waves).
// B streamed through 20KB padded LDS (k=32 slabs); g1 in 32KB swizzled LDS.
// 52KB LDS -> 3 blocks/CU (12 waves).
// ---------------------------------------------------------------------------
__global__ __launch_bounds__(256, 3) void gate_k(
    const f16* __restrict__ base, const f16* __restrict__ norms,
    const f16* __restrict__ Wg1T, const f16* __restrict__ Wg2T,
    const float* __restrict__ bg1, const float* __restrict__ bg2,
    f16* __restrict__ g2out)
{
    const int l  = blockIdx.y;
    const int n0 = blockIdx.x * 64;
    const int t  = threadIdx.x;
    const int wv = t >> 6, ln = t & 63;
    const int col0 = ln & 15, kq = ln >> 4;

    __shared__ f16 bs[256][40];      // [n=256][k=32] pad->40 (2-way max), 20KB
    __shared__ f16 g1l[64 * 256];    // swizzled, 32KB

    const int anode = n0 + wv * 16 + col0;
    const bool aok = anode < NNODES;

    f32x4 acc[16];
    #pragma unroll
    for (int nt = 0; nt < 16; ++nt) {
        float b = bg1[l * 256 + nt * 16 + col0];
        f32x4 v = {b, b, b, b};
        acc[nt] = v;
    }

    const f16* wg1 = Wg1T + (size_t)l * 131072;
    #pragma unroll
    for (int slab = 0; slab < 16; ++slab) {
        // stage B slab: 256 rows x 32 k  (1024 granules / 256 thr = 4 each)
        #pragma unroll
        for (int it = 0; it < 4; ++it) {
            int idx = t + 256 * it;
            int row = idx >> 2, g = idx & 3;
            *(f16x8*)&bs[row][g * 8] =
                *(const f16x8*)(wg1 + (size_t)row * 512 + slab * 32 + g * 8);
        }
        __syncthreads();
        const f16* asrc;
        if (slab < 8)       asrc = base  + (size_t)anode * 384 + slab * 32;
        else if (slab < 12) asrc = norms + ((size_t)l * NNODES + anode) * 128 + (slab - 8) * 32;
        else                asrc = base  + (size_t)anode * 384 + 256 + (slab - 12) * 32;
        f16x8 a = zero8();
        if (aok) a = *(const f16x8*)(asrc + kq * 8);
        #pragma unroll
        for (int nt = 0; nt < 16; ++nt) {
            f16x8 b = *(const f16x8*)&bs[nt * 16 + col0][kq * 8];
            acc[nt] = __builtin_amdgcn_mfma_f32_16x16x32_f16(a, b, acc[nt], 0, 0, 0);
        }
        __syncthreads();
    }

    // g1 = silu(acc) -> swizzled LDS (wave-local rows)
    #pragma unroll
    for (int nt = 0; nt < 16; ++nt)
        #pragma unroll
        for (int j = 0; j < 4; ++j) {
            int row = wv * 16 + kq * 4 + j;
            int col = nt * 16 + col0;
            int g = (col >> 3) ^ (row & 7);
            g1l[row * 256 + g * 8 + (col & 7)] = (f16)silu(acc[nt][j]);
        }

    f32x4 acc2[16];
    #pragma unroll
    for (int nt = 0; nt < 16; ++nt) {
        float b = bg2[l * 256 + nt * 16 + col0];
        f32x4 v = {b, b, b, b};
        acc2[nt] = v;
    }
    const f16* wg2 = Wg2T + (size_t)l * 65536;
    #pragma unroll
    for (int slab = 0; slab < 8; ++slab) {
        #pragma unroll
        for (int it = 0; it < 4; ++it) {
            int idx = t + 256 * it;
            int row = idx >> 2, g = idx & 3;
            *(f16x8*)&bs[row][g * 8] =
                *(const f16x8*)(wg2 + (size_t)row * 256 + slab * 32 + g * 8);
        }
        __syncthreads();
        int arow = wv * 16 + col0;
        int gk = slab * 4 + kq;                     // global k-granule 0..31
        f16x8 a = *(const f16x8*)&g1l[arow * 256 + (gk ^ (arow & 7)) * 8];
        #pragma unroll
        for (int nt = 0; nt < 16; ++nt) {
            f16x8 b = *(const f16x8*)&bs[nt * 16 + col0][kq * 8];
            acc2[nt] = __builtin_amdgcn_mfma_f32_16x16x32_f16(a, b, acc2[nt], 0, 0, 0);
        }
        __syncthreads();
    }

    // g2 = silu(acc2) -> g1l (reuse), then coalesced swizzle-aware copy out
    #pragma unroll
    for (int nt = 0; nt < 16; ++nt)
        #pragma unroll
        for (int j = 0; j < 4; ++j) {
            int row = wv * 16 + kq * 4 + j;
            int col = nt * 16 + col0;
            int g = (col >> 3) ^ (row & 7);
            g1l[row * 256 + g * 8 + (col & 7)] = (f16)silu(acc2[nt][j]);
        }
    __syncthreads();
    #pragma unroll
    for (int it = 0; it < 8; ++it) {
        int idx = t + 256 * it;          // 2048 granules
        int row = idx >> 5, g = idx & 31;
        int node = n0 + row;
        if (node < NNODES) {
            f16x8 v = *(const f16x8*)&g1l[row * 256 + (g ^ (row & 7)) * 8];
            *(f16x8*)(g2out + ((size_t)l * NNODES + node) * 256 + g * 8) = v;
        }
    }
}

// ---------------------------------------------------------------------------
// mk: fused h = x@W1 -> (silu l0) -> LDS; out = (h.*g)@W2.
// 64 rows/block, 256 threads (4 waves). W1/W2 double-buffered k=32 slabs
// (40KB) + h tile (33.8KB) = 73.8KB -> 2 blocks/CU. A row (x) and g row
// prefetched to regs; out stores nontemporal.
// ---------------------------------------------------------------------------
__global__ __launch_bounds__(256, 2) void mk_k(
    const float* __restrict__ x, const f16* __restrict__ g2,
    const f16* __restrict__ W1T, const f16* __restrict__ W2T,
    float* __restrict__ out)
{
    const int t  = threadIdx.x;
    const int wv = t >> 6, ln = t & 63;
    const int col0 = ln & 15, kq = ln >> 4;
    const int r0 = blockIdx.x * 64;

    __shared__ f16 bs[2][256][40];   // W slabs, double-buffered (40KB)
    __shared__ f16 hld[64][264];     // h tile (33.8KB)

    const int arow = r0 + wv * 16 + col0;
    const bool aok = arow < TOTROWS;
    const int ar  = aok ? arow : 0;
    const int node = ar / 9;
    const int p    = ar - node * 9;
    const int lsel = (p > 0) + (p > 3);
    const float* asrc = x + (size_t)ar * 128;
    const f16* grow = g2 + ((size_t)lsel * NNODES + node) * 256;

    // ---- prefetch A row (x, f32->f16, NT) and gate row into regs ----
    f16x8 ax[4];
    #pragma unroll
    for (int ks = 0; ks < 4; ++ks) {
        ax[ks] = zero8();
        if (aok) {
            f32x4 f0 = __builtin_nontemporal_load((const f32x4*)(asrc + ks * 32 + kq * 8));
            f32x4 f1 = __builtin_nontemporal_load((const f32x4*)(asrc + ks * 32 + kq * 8 + 4));
            #pragma unroll
            for (int i = 0; i < 4; ++i) {
                ax[ks][i]     = (f16)f0[i];
                ax[ks][4 + i] = (f16)f1[i];
            }
        }
    }
    f16x8 gpre[8];
    #pragma unroll
    for (int ks = 0; ks < 8; ++ks) {
        gpre[ks] = zero8();
        if (aok) gpre[ks] = *(const f16x8*)(grow + ks * 32 + kq * 8);
    }

    // ---- GEMM1: h = x @ W1, W1 in k=32 slabs (4), double-buffered ----
    {   // stage slab 0
        #pragma unroll
        for (int it = 0; it < 4; ++it) {
            int idx = t + 256 * it;
            int row = idx >> 2, g = idx & 3;
            *(f16x8*)&bs[0][row][g * 8] =
                *(const f16x8*)(W1T + (size_t)row * 128 + 0 * 32 + g * 8);
        }
    }
    __syncthreads();

    f32x4 acc[16];
    #pragma unroll
    for (int nt = 0; nt < 16; ++nt) { f32x4 z = {0,0,0,0}; acc[nt] = z; }
    #pragma unroll
    for (int s = 0; s < 4; ++s) {
        if (s < 3) {   // stage next slab into other buffer
            #pragma unroll
            for (int it = 0; it < 4; ++it) {
                int idx = t + 256 * it;
                int row = idx >> 2, g = idx & 3;
                *(f16x8*)&bs[(s + 1) & 1][row][g * 8] =
                    *(const f16x8*)(W1T + (size_t)row * 128 + (s + 1) * 32 + g * 8);
            }
        }
        #pragma unroll
        for (int nt = 0; nt < 16; ++nt) {
            f16x8 b = *(const f16x8*)&bs[s & 1][nt * 16 + col0][kq * 8];
            acc[nt] = __builtin_amdgcn_mfma_f32_16x16x32_f16(ax[s], b, acc[nt], 0, 0, 0);
        }
        __syncthreads();
    }

    // ---- h (silu on l=0 rows) -> hld ----
    #pragma unroll
    for (int j = 0; j < 4; ++j) {
        int rl = wv * 16 + kq * 4 + j;
        int pj = (r0 + rl) % 9;
        if (pj == 0) {
            #pragma unroll
            for (int nt = 0; nt < 16; ++nt)
                hld[rl][nt * 16 + col0] = (f16)silu(acc[nt][j]);
        } else {
            #pragma unroll
            for (int nt = 0; nt < 16; ++nt)
                hld[rl][nt * 16 + col0] = (f16)acc[nt][j];
        }
    }

    // ---- GEMM2: out = (h .* g) @ W2, W2 in k=32 slabs (8), db ----
    {   // stage W2 slab 0 (buffer 0 free: last GEMM1 compute used buf 1)
        #pragma unroll
        for (int it = 0; it < 2; ++it) {
            int idx = t + 256 * it;
            int row = idx >> 2, g = idx & 3;
            *(f16x8*)&bs[0][row][g * 8] =
                *(const f16x8*)(W2T + (size_t)row * 256 + 0 * 32 + g * 8);
        }
    }
    __syncthreads();

    f32x4 acc2[8];
    #pragma unroll
    for (int nt = 0; nt < 8; ++nt) { f32x4 z = {0,0,0,0}; acc2[nt] = z; }
    #pragma unroll
    for (int s = 0; s < 8; ++s) {
        if (s < 7) {
            #pragma unroll
            for (int it = 0; it < 2; ++it) {
                int idx = t + 256 * it;
                int row = idx >> 2, g = idx & 3;
                *(f16x8*)&bs[(s + 1) & 1][row][g * 8] =
                    *(const f16x8*)(W2T + (size_t)row * 256 + (s + 1) * 32 + g * 8);
            }
        }
        f16x8 h8 = *(const f16x8*)&hld[wv * 16 + col0][s * 32 + kq * 8];
        f16x8 a;
        #pragma unroll
        for (int i = 0; i < 8; ++i)
            a[i] = (f16)((float)h8[i] * (float)gpre[s][i]);
        #pragma unroll
        for (int nt = 0; nt < 8; ++nt) {
            f16x8 b = *(const f16x8*)&bs[s & 1][nt * 16 + col0][kq * 8];
            acc2[nt] = __builtin_amdgcn_mfma_f32_16x16x32_f16(a, b, acc2[nt], 0, 0, 0);
        }
        __syncthreads();
    }
    #pragma unroll
    for (int j = 0; j < 4; ++j) {
        int gr = r0 + wv * 16 + kq * 4 + j;
        if (gr < TOTROWS) {
            #pragma unroll
            for (int nt = 0; nt < 8; ++nt)
                __builtin_nontemporal_store(acc2[nt][j],
                    out + (size_t)gr * 128 + nt * 16 + col0);
        }
    }
}

// ---------------------------------------------------------------------------
extern "C" void kernel_launch(void* const* d_in, const int* in_sizes, int n_in,
                              void* d_out, int out_size, void* d_ws, size_t ws_size,
                              hipStream_t stream) {
    const float* x_emb = (const float*)d_in[0];
    const float* t_ij  = (const float*)d_in[1];
    const float* a_ij  = (const float*)d_in[2];
    const int*   eidx  = (const int*)d_in[3];
    const float* W1  = (const float*)d_in[4];
    const float* W2  = (const float*)d_in[5];
    const float* Wg1 = (const float*)d_in[6];
    const float* bg1 = (const float*)d_in[7];
    const float* Wg2 = (const float*)d_in[8];
    const float* bg2 = (const float*)d_in[9];
    float* out = (float*)d_out;
    const int* dst = eidx + NEDGES;

    char* p = (char*)d_ws;
    int* cnt       = (int*)p;                 p += (size_t)NNODES * 4;
    int* cur       = (int*)p;                 p += (size_t)NNODES * 4;
    int* row_start = (int*)p;                 p += (size_t)(NNODES + 16) * 4;
    int* eids      = (int*)p;                 p += (size_t)NEDGES * 4;
    f16* base      = (f16*)p;                 p += (size_t)NNODES * 384 * 2;
    f16* norms     = (f16*)p;                 p += (size_t)3 * NNODES * 128 * 2;
    f16* g2b       = (f16*)p;                 p += (size_t)3 * NNODES * 256 * 2;
    f16* W1T       = (f16*)p;                 p += (size_t)32768 * 2;
    f16* W2T       = (f16*)p;                 p += (size_t)32768 * 2;
    f16* Wg1T      = (f16*)p;                 p += (size_t)393216 * 2;
    f16* Wg2T      = (f16*)p;                 p += (size_t)196608 * 2;

    hipMemsetAsync(cnt, 0, (size_t)2 * NNODES * 4, stream);  // cnt + cur

    wprep_k<<<1536, 256, 0, stream>>>(W1, W2, Wg1, Wg2, W1T, W2T, Wg1T, Wg2T);
    prep_k<<<NNODES / 8, 256, 0, stream>>>(x_emb, base, norms);
    hist_k<<<NEDGES / 256, 256, 0, stream>>>(dst, cnt);
    scan_k<<<1, 1024, 0, stream>>>(cnt, row_start);
    fill_k<<<NEDGES / 256, 256, 0, stream>>>(dst, row_start, cur, eids);
    gather_k<<<NNODES / 4, 256, 0, stream>>>(t_ij, a_ij, row_start, cnt, eids, base);
    dim3 gg((NNODES + 63) / 64, 3);
    gate_k<<<gg, 256, 0, stream>>>(base, norms, Wg1T, Wg2T, bg1, bg2, g2b);
    mk_k<<<MKBLK, 256, 0, stream>>>(x_emb, g2b, W1T, W2T, out);
}

// Round 10
// 677.367 us; speedup vs baseline: 3.2128x; 1.0422x over previous
//
#include <hip/hip_runtime.h>
#include <hip/hip_bf16.h>
#include <math.h>

#define NNODES 50000
#define NEDGES 800000
#define NROWS  9
#define TOTROWS (NNODES * NROWS)   // 450000
#define MKBLK  7032                // ceil(450000/64)

typedef _Float16 f16;
typedef _Float16 f16x8 __attribute__((ext_vector_type(8)));
typedef _Float16 f16x4 __attribute__((ext_vector_type(4)));
typedef float    f32x4 __attribute__((ext_vector_type(4)));

__device__ __forceinline__ float silu(float x) { return x / (1.0f + __expf(-x)); }

__device__ __forceinline__ f16x8 zero8() {
    f16x8 v;
    #pragma unroll
    for (int i = 0; i < 8; ++i) v[i] = (f16)0.0f;
    return v;
}

// ---------------------------------------------------------------------------
// front_k: fused wprep (blocks [0,1536)) + prep ([1536,7786)) + hist (rest).
// All three are independent; fusing overlaps hist's atomic latency with
// prep's 230MB stream and saves 2 launch gaps.
// ---------------------------------------------------------------------------
__global__ __launch_bounds__(256) void front_k(
    const float* __restrict__ W1, const float* __restrict__ W2,
    const float* __restrict__ Wg1, const float* __restrict__ Wg2,
    f16* __restrict__ W1T, f16* __restrict__ W2T,
    f16* __restrict__ Wg1T, f16* __restrict__ Wg2T,
    const float* __restrict__ x, f16* __restrict__ base, f16* __restrict__ norms,
    const int* __restrict__ dst, int* __restrict__ cnt)
{
    const int b = blockIdx.x;
    const int t = threadIdx.x;
    if (b < 1536) {
        // ---- weight transpose + f16 convert; dest [out_col][k] ----
        int i = b * 256 + t;
        if (i < 32768) {  // W1T[n=256][k=128]
            int n = i >> 7, k = i & 127;
            W1T[i] = (f16)W1[k * 256 + n];
        }
        if (i < 32768) {  // W2T[s=128][k=256]
            int s = i >> 8, k = i & 255;
            W2T[i] = (f16)W2[k * 128 + s];
        }
        if (i < 393216) { // Wg1T[l][h=256][k=512]
            int l = i >> 17, r = i & 131071;
            int h = r >> 9, k = r & 511;
            Wg1T[i] = (f16)Wg1[l * 131072 + k * 256 + h];
        }
        if (i < 196608) { // Wg2T[l][h=256][k=256]
            int l = i >> 16, r = i & 65535;
            int h = r >> 8, k = r & 255;
            Wg2T[i] = (f16)Wg2[l * 65536 + k * 256 + h];
        }
    } else if (b < 1536 + 6250) {
        // ---- per-node prep: x0 slot of base + norms ----
        int node = (b - 1536) * 8 + (t >> 5);
        int c4 = (t & 31) * 4;
        const float* xr = x + (size_t)node * (NROWS * 128) + c4;
        f32x4 v0 = *(const f32x4*)xr;
        f32x4 s1 = {0,0,0,0}, s2 = {0,0,0,0};
        #pragma unroll
        for (int r = 1; r < 4; ++r) { f32x4 v = *(const f32x4*)(xr + r * 128); s1 += v * v; }
        #pragma unroll
        for (int r = 4; r < 9; ++r) { f32x4 v = *(const f32x4*)(xr + r * 128); s2 += v * v; }
        f16x4 b0, n0v, n1v, n2v;
        #pragma unroll
        for (int i = 0; i < 4; ++i) {
            b0[i]  = (f16)v0[i];
            n0v[i] = (f16)fabsf(v0[i]);
            n1v[i] = (f16)sqrtf(s1[i]);
            n2v[i] = (f16)sqrtf(s2[i]);
        }
        *(f16x4*)(base + (size_t)node * 384 + 256 + c4) = b0;
        *(f16x4*)(norms + (size_t)node * 128 + c4) = n0v;
        *(f16x4*)(norms + ((size_t)NNODES + node) * 128 + c4) = n1v;
        *(f16x4*)(norms + ((size_t)2 * NNODES + node) * 128 + c4) = n2v;
    } else {
        // ---- histogram ----
        int e = (b - 1536 - 6250) * 256 + t;
        if (e < NEDGES) atomicAdd(&cnt[dst[e]], 1);
    }
}

// ---------------------------------------------------------------------------
// CSR scan + fill
// ---------------------------------------------------------------------------
__global__ __launch_bounds__(1024) void scan_k(const int* __restrict__ cnt, int* __restrict__ row_start)
{
    __shared__ int part[1024];
    int t = threadIdx.x;
    int lo = t * 49, hi = min(lo + 49, NNODES);
    int s = 0;
    for (int i = lo; i < hi; ++i) s += cnt[i];
    part[t] = s;
    __syncthreads();
    for (int off = 1; off < 1024; off <<= 1) {
        int v = (t >= off) ? part[t - off] : 0;
        __syncthreads();
        part[t] += v;
        __syncthreads();
    }
    int run = part[t] - s;
    for (int i = lo; i < hi; ++i) { row_start[i] = run; run += cnt[i]; }
}

__global__ __launch_bounds__(256) void fill_k(
    const int* __restrict__ dst, const int* __restrict__ row_start,
    int* __restrict__ cur, int* __restrict__ eids)
{
    int e = blockIdx.x * 256 + threadIdx.x;
    if (e >= NEDGES) return;
    int d = dst[e];
    int p = atomicAdd(&cur[d], 1);
    eids[row_start[d] + p] = e;
}

// ---------------------------------------------------------------------------
// Gather means: wave per node. Coalesced eids load (64/chunk) + shfl
// broadcast with WAVE-UNIFORM control flow; unroll 2 -> 32 loads in flight.
// ---------------------------------------------------------------------------
__global__ __launch_bounds__(256) void gather_k(
    const float* __restrict__ t_ij, const float* __restrict__ a_ij,
    const int* __restrict__ row_start, const int* __restrict__ cnt,
    const int* __restrict__ eids, f16* __restrict__ base)
{
    int wv = threadIdx.x >> 6, ln = threadIdx.x & 63;
    int node = blockIdx.x * 4 + wv;
    int rs = row_start[node];
    int n  = cnt[node];
    int qw = ln >> 4, q = ln & 15;
    f32x4 tc0 = {0,0,0,0}, tc1 = {0,0,0,0}, ac0 = {0,0,0,0}, ac1 = {0,0,0,0};
    for (int b0 = 0; b0 < n; b0 += 64) {          // wave-uniform bound
        int ecnt = min(64, n - b0);
        int eid = (b0 + ln < n) ? eids[rs + b0 + ln] : 0;
        #pragma unroll 2
        for (int i0 = 0; i0 < ecnt; i0 += 4) {    // wave-uniform bound
            int i = i0 + qw;                       // this lane's edge in group
            int e = __shfl(eid, i & 63);           // all 64 lanes execute
            if (i < ecnt) {
                const f32x4* tr = (const f32x4*)(t_ij + (size_t)e * 128 + q * 8);
                const f32x4* ar = (const f32x4*)(a_ij + (size_t)e * 128 + q * 8);
                f32x4 t0 = __builtin_nontemporal_load(tr);
                f32x4 t1 = __builtin_nontemporal_load(tr + 1);
                f32x4 a0 = __builtin_nontemporal_load(ar);
                f32x4 a1 = __builtin_nontemporal_load(ar + 1);
                tc0 += t0; tc1 += t1; ac0 += a0; ac1 += a1;
            }
        }
    }
    #pragma unroll
    for (int m = 16; m <= 32; m <<= 1) {
        #pragma unroll
        for (int i = 0; i < 4; ++i) {
            tc0[i] += __shfl_xor(tc0[i], m);
            tc1[i] += __shfl_xor(tc1[i], m);
            ac0[i] += __shfl_xor(ac0[i], m);
            ac1[i] += __shfl_xor(ac1[i], m);
        }
    }
    float inv = 1.0f / (float)(n > 0 ? n : 1);
    if (qw == 0) {          // c_i channels q*8..q*8+7
        f16x8 v;
        #pragma unroll
        for (int i = 0; i < 4; ++i) {
            v[i]     = (f16)(tc0[i] * inv);
            v[4 + i] = (f16)(tc1[i] * inv);
        }
        *(f16x8*)(base + (size_t)node * 384 + q * 8) = v;
    } else if (qw == 1) {   // c_ang
        f16x8 v;
        #pragma unroll
        for (int i = 0; i < 4; ++i) {
            v[i]     = (f16)(ac0[i] * inv);
            v[4 + i] = (f16)(ac1[i] * inv);
        }
        *(f16x8*)(base + (size_t)node * 384 + 128 + q * 8) = v;
    }
}

// ---------------------------------------------------------------------------
// Gate MLP, one l per blockIdx.y. 64 nodes/block, 256 threads (4 waves).
// B streamed through 20KB padded LDS (k=32 slabs); g1 in 32KB swizzled LDS.
// 52KB LDS -> 3 blocks/CU (12 waves).
// ---------------------------------------------------------------------------
__global__ __launch_bounds__(256, 3) void gate_k(
    const f16* __restrict__ base, const f16* __restrict__ norms,
    const f16* __restrict__ Wg1T, const f16* __restrict__ Wg2T,
    const float* __restrict__ bg1, const float* __restrict__ bg2,
    f16* __restrict__ g2out)
{
    const int l  = blockIdx.y;
    const int n0 = blockIdx.x * 64;
    const int t  = threadIdx.x;
    const int wv = t >> 6, ln = t & 63;
    const int col0 = ln & 15, kq = ln >> 4;

    __shared__ f16 bs[256][40];      // [n=256][k=32] pad->40 (2-way max), 20KB
    __shared__ f16 g1l[64 * 256];    // swizzled, 32KB

    const int anode = n0 + wv * 16 + col0;
    const bool aok = anode < NNODES;

    f32x4 acc[16];
    #pragma unroll
    for (int nt = 0; nt < 16; ++nt) {
        float b = bg1[l * 256 + nt * 16 + col0];
        f32x4 v = {b, b, b, b};
        acc[nt] = v;
    }

    const f16* wg1 = Wg1T + (size_t)l * 131072;
    #pragma unroll
    for (int slab = 0; slab < 16; ++slab) {
        #pragma unroll
        for (int it = 0; it < 4; ++it) {
            int idx = t + 256 * it;
            int row = idx >> 2, g = idx & 3;
            *(f16x8*)&bs[row][g * 8] =
                *(const f16x8*)(wg1 + (size_t)row * 512 + slab * 32 + g * 8);
        }
        __syncthreads();
        const f16* asrc;
        if (slab < 8)       asrc = base  + (size_t)anode * 384 + slab * 32;
        else if (slab < 12) asrc = norms + ((size_t)l * NNODES + anode) * 128 + (slab - 8) * 32;
        else                asrc = base  + (size_t)anode * 384 + 256 + (slab - 12) * 32;
        f16x8 a = zero8();
        if (aok) a = *(const f16x8*)(asrc + kq * 8);
        #pragma unroll
        for (int nt = 0; nt < 16; ++nt) {
            f16x8 b = *(const f16x8*)&bs[nt * 16 + col0][kq * 8];
            acc[nt] = __builtin_amdgcn_mfma_f32_16x16x32_f16(a, b, acc[nt], 0, 0, 0);
        }
        __syncthreads();
    }

    // g1 = silu(acc) -> swizzled LDS (wave-local rows)
    #pragma unroll
    for (int nt = 0; nt < 16; ++nt)
        #pragma unroll
        for (int j = 0; j < 4; ++j) {
            int row = wv * 16 + kq * 4 + j;
            int col = nt * 16 + col0;
            int g = (col >> 3) ^ (row & 7);
            g1l[row * 256 + g * 8 + (col & 7)] = (f16)silu(acc[nt][j]);
        }

    f32x4 acc2[16];
    #pragma unroll
    for (int nt = 0; nt < 16; ++nt) {
        float b = bg2[l * 256 + nt * 16 + col0];
        f32x4 v = {b, b, b, b};
        acc2[nt] = v;
    }
    const f16* wg2 = Wg2T + (size_t)l * 65536;
    #pragma unroll
    for (int slab = 0; slab < 8; ++slab) {
        #pragma unroll
        for (int it = 0; it < 4; ++it) {
            int idx = t + 256 * it;
            int row = idx >> 2, g = idx & 3;
            *(f16x8*)&bs[row][g * 8] =
                *(const f16x8*)(wg2 + (size_t)row * 256 + slab * 32 + g * 8);
        }
        __syncthreads();
        int arow = wv * 16 + col0;
        int gk = slab * 4 + kq;                     // global k-granule 0..31
        f16x8 a = *(const f16x8*)&g1l[arow * 256 + (gk ^ (arow & 7)) * 8];
        #pragma unroll
        for (int nt = 0; nt < 16; ++nt) {
            f16x8 b = *(const f16x8*)&bs[nt * 16 + col0][kq * 8];
            acc2[nt] = __builtin_amdgcn_mfma_f32_16x16x32_f16(a, b, acc2[nt], 0, 0, 0);
        }
        __syncthreads();
    }

    // g2 = silu(acc2) -> g1l (reuse), then coalesced swizzle-aware copy out
    #pragma unroll
    for (int nt = 0; nt < 16; ++nt)
        #pragma unroll
        for (int j = 0; j < 4; ++j) {
            int row = wv * 16 + kq * 4 + j;
            int col = nt * 16 + col0;
            int g = (col >> 3) ^ (row & 7);
            g1l[row * 256 + g * 8 + (col & 7)] = (f16)silu(acc2[nt][j]);
        }
    __syncthreads();
    #pragma unroll
    for (int it = 0; it < 8; ++it) {
        int idx = t + 256 * it;          // 2048 granules
        int row = idx >> 5, g = idx & 31;
        int node = n0 + row;
        if (node < NNODES) {
            f16x8 v = *(const f16x8*)&g1l[row * 256 + (g ^ (row & 7)) * 8];
            *(f16x8*)(g2out + ((size_t)l * NNODES + node) * 256 + g * 8) = v;
        }
    }
}

// ---------------------------------------------------------------------------
// mk: fused h = x@W1 -> (silu l0) -> swizzled LDS; out = (h.*g)@W2.
// 64 rows/block, 256 threads. gate_k's single-buffered slab structure:
// bs 20KB + swizzled hl 32.75KB = 52.75KB -> 3 blocks/CU (12 waves).
// ---------------------------------------------------------------------------
__global__ __launch_bounds__(256, 3) void mk_k(
    const float* __restrict__ x, const f16* __restrict__ g2,
    const f16* __restrict__ W1T, const f16* __restrict__ W2T,
    float* __restrict__ out)
{
    const int t  = threadIdx.x;
    const int wv = t >> 6, ln = t & 63;
    const int col0 = ln & 15, kq = ln >> 4;
    const int r0 = blockIdx.x * 64;

    __shared__ f16 bs[256][40];      // W slab [rows][k=32] pad->40, 20KB
    __shared__ f16 hl[64 * 256];     // h tile, swizzled, 32.75KB

    const int arow = r0 + wv * 16 + col0;
    const bool aok = arow < TOTROWS;
    const int ar  = aok ? arow : 0;
    const int node = ar / 9;
    const int p    = ar - node * 9;
    const int lsel = (p > 0) + (p > 3);
    const float* asrc = x + (size_t)ar * 128;
    const f16* grow = g2 + ((size_t)lsel * NNODES + node) * 256;

    // ---- prefetch A row (x, f32->f16, NT) and gate row into regs ----
    f16x8 ax[4];
    #pragma unroll
    for (int ks = 0; ks < 4; ++ks) {
        ax[ks] = zero8();
        if (aok) {
            f32x4 f0 = __builtin_nontemporal_load((const f32x4*)(asrc + ks * 32 + kq * 8));
            f32x4 f1 = __builtin_nontemporal_load((const f32x4*)(asrc + ks * 32 + kq * 8 + 4));
            #pragma unroll
            for (int i = 0; i < 4; ++i) {
                ax[ks][i]     = (f16)f0[i];
                ax[ks][4 + i] = (f16)f1[i];
            }
        }
    }
    f16x8 gpre[8];
    #pragma unroll
    for (int ks = 0; ks < 8; ++ks) {
        gpre[ks] = zero8();
        if (aok) gpre[ks] = *(const f16x8*)(grow + ks * 32 + kq * 8);
    }

    // ---- GEMM1: h = x @ W1, W1 in k=32 slabs (4), single-buffered ----
    f32x4 acc[16];
    #pragma unroll
    for (int nt = 0; nt < 16; ++nt) { f32x4 z = {0,0,0,0}; acc[nt] = z; }
    #pragma unroll
    for (int s = 0; s < 4; ++s) {
        #pragma unroll
        for (int it = 0; it < 4; ++it) {   // 1024 granules: 256 rows x 4
            int idx = t + 256 * it;
            int row = idx >> 2, g = idx & 3;
            *(f16x8*)&bs[row][g * 8] =
                *(const f16x8*)(W1T + (size_t)row * 128 + s * 32 + g * 8);
        }
        __syncthreads();
        #pragma unroll
        for (int nt = 0; nt < 16; ++nt) {
            f16x8 b = *(const f16x8*)&bs[nt * 16 + col0][kq * 8];
            acc[nt] = __builtin_amdgcn_mfma_f32_16x16x32_f16(ax[s], b, acc[nt], 0, 0, 0);
        }
        __syncthreads();
    }

    // ---- h (silu on l=0 rows) -> hl swizzled (wave-local rows) ----
    #pragma unroll
    for (int j = 0; j < 4; ++j) {
        int rl = wv * 16 + kq * 4 + j;
        int pj = (r0 + rl) % 9;
        if (pj == 0) {
            #pragma unroll
            for (int nt = 0; nt < 16; ++nt) {
                int col = nt * 16 + col0;
                int g = (col >> 3) ^ (rl & 7);
                hl[rl * 256 + g * 8 + (col & 7)] = (f16)silu(acc[nt][j]);
            }
        } else {
            #pragma unroll
            for (int nt = 0; nt < 16; ++nt) {
                int col = nt * 16 + col0;
                int g = (col >> 3) ^ (rl & 7);
                hl[rl * 256 + g * 8 + (col & 7)] = (f16)acc[nt][j];
            }
        }
    }
    // no barrier: GEMM2's A-rows (wv*16+col0) are wave-local; lgkmcnt orders

    // ---- GEMM2: out = (h .* g) @ W2, W2 in k=32 slabs (8), single-buf ----
    f32x4 acc2[8];
    #pragma unroll
    for (int nt = 0; nt < 8; ++nt) { f32x4 z = {0,0,0,0}; acc2[nt] = z; }
    const int arow2 = wv * 16 + col0;
    #pragma unroll
    for (int s = 0; s < 8; ++s) {
        #pragma unroll
        for (int it = 0; it < 2; ++it) {   // 512 granules: 128 rows x 4
            int idx = t + 256 * it;
            int row = idx >> 2, g = idx & 3;
            *(f16x8*)&bs[row][g * 8] =
                *(const f16x8*)(W2T + (size_t)row * 256 + s * 32 + g * 8);
        }
        __syncthreads();
        int gk = s * 4 + kq;
        f16x8 h8 = *(const f16x8*)&hl[arow2 * 256 + (gk ^ (arow2 & 7)) * 8];
        f16x8 a;
        #pragma unroll
        for (int i = 0; i < 8; ++i)
            a[i] = (f16)((float)h8[i] * (float)gpre[s][i]);
        #pragma unroll
        for (int nt = 0; nt < 8; ++nt) {
            f16x8 b = *(const f16x8*)&bs[nt * 16 + col0][kq * 8];
            acc2[nt] = __builtin_amdgcn_mfma_f32_16x16x32_f16(a, b, acc2[nt], 0, 0, 0);
        }
        __syncthreads();
    }
    #pragma unroll
    for (int j = 0; j < 4; ++j) {
        int gr = r0 + wv * 16 + kq * 4 + j;
        if (gr < TOTROWS) {
            #pragma unroll
            for (int nt = 0; nt < 8; ++nt)
                __builtin_nontemporal_store(acc2[nt][j],
                    out + (size_t)gr * 128 + nt * 16 + col0);
        }
    }
}

// ---------------------------------------------------------------------------
extern "C" void kernel_launch(void* const* d_in, const int* in_sizes, int n_in,
                              void* d_out, int out_size, void* d_ws, size_t ws_size,
                              hipStream_t stream) {
    const float* x_emb = (const float*)d_in[0];
    const float* t_ij  = (const float*)d_in[1];
    const float* a_ij  = (const float*)d_in[2];
    const int*   eidx  = (const int*)d_in[3];
    const float* W1  = (const float*)d_in[4];
    const float* W2  = (const float*)d_in[5];
    const float* Wg1 = (const float*)d_in[6];
    const float* bg1 = (const float*)d_in[7];
    const float* Wg2 = (const float*)d_in[8];
    const float* bg2 = (const float*)d_in[9];
    float* out = (float*)d_out;
    const int* dst = eidx + NEDGES;

    char* p = (char*)d_ws;
    int* cnt       = (int*)p;                 p += (size_t)NNODES * 4;
    int* cur       = (int*)p;                 p += (size_t)NNODES * 4;
    int* row_start = (int*)p;                 p += (size_t)(NNODES + 16) * 4;
    int* eids      = (int*)p;                 p += (size_t)NEDGES * 4;
    f16* base      = (f16*)p;                 p += (size_t)NNODES * 384 * 2;
    f16* norms     = (f16*)p;                 p += (size_t)3 * NNODES * 128 * 2;
    f16* g2b       = (f16*)p;                 p += (size_t)3 * NNODES * 256 * 2;
    f16* W1T       = (f16*)p;                 p += (size_t)32768 * 2;
    f16* W2T       = (f16*)p;                 p += (size_t)32768 * 2;
    f16* Wg1T      = (f16*)p;                 p += (size_t)393216 * 2;
    f16* Wg2T      = (f16*)p;                 p += (size_t)196608 * 2;

    hipMemsetAsync(cnt, 0, (size_t)2 * NNODES * 4, stream);  // cnt + cur

    front_k<<<1536 + 6250 + 3125, 256, 0, stream>>>(
        W1, W2, Wg1, Wg2, W1T, W2T, Wg1T, Wg2T, x_emb, base, norms, dst, cnt);
    scan_k<<<1, 1024, 0, stream>>>(cnt, row_start);
    fill_k<<<NEDGES / 256, 256, 0, stream>>>(dst, row_start, cur, eids);
    gather_k<<<NNODES / 4, 256, 0, stream>>>(t_ij, a_ij, row_start, cnt, eids, base);
    dim3 gg((NNODES + 63) / 64, 3);
    gate_k<<<gg, 256, 0, stream>>>(base, norms, Wg1T, Wg2T, bg1, bg2, g2b);
    mk_k<<<MKBLK, 256, 0, stream>>>(x_emb, g2b, W1T, W2T, out);
}